// Round 12
// baseline (5569.487 us; speedup 1.0000x reference)
//
#include <hip/hip_runtime.h>
#include <math.h>

#define BLK 256
static constexpr float MU_F  = 0.1f;
static constexpr float THR_F = 0.01f;

typedef __attribute__((ext_vector_type(8))) short bf16x8;
typedef __attribute__((ext_vector_type(4))) float f32x4;

__device__ inline unsigned short f2bf(float f) {
    unsigned u = __float_as_uint(f);
    unsigned r = (u + 0x7fffu + ((u >> 16) & 1u)) >> 16;   // RNE
    return (unsigned short)r;
}
__device__ inline float bf2f(unsigned short h) {
    return __uint_as_float(((unsigned)h) << 16);
}

// ---------------- block reduction ----------------
__device__ inline float blk_reduce(float v) {
    __shared__ float sh[BLK];
    int tid = threadIdx.x;
    sh[tid] = v;
    __syncthreads();
    #pragma unroll
    for (int s = BLK / 2; s > 0; s >>= 1) {
        if (tid < s) sh[tid] += sh[tid + s];
        __syncthreads();
    }
    float r = sh[0];
    __syncthreads();
    return r;
}

// ---------------- fp32 normalize + pack (L0, L5) ----------------
__global__ __launch_bounds__(BLK) void wnorm_pack(
    const float* __restrict__ W, float* __restrict__ Wkc,
    float* __restrict__ Wnout, int Mout, int asz)
{
    int o = blockIdx.x;
    const float* w = W + (size_t)o * asz;
    float s = 0.f;
    for (int i = threadIdx.x; i < asz; i += BLK) { float v = w[i]; s = fmaf(v, v, s); }
    float tot = blk_reduce(s);
    float inv = 1.0f / (sqrtf(tot) + 1e-12f);
    for (int i = threadIdx.x; i < asz; i += BLK) {
        float v = w[i] * inv;
        Wkc[(size_t)i * Mout + o] = v;
        if (Wnout) Wnout[(size_t)o * asz + i] = v;
    }
}

// ---------------- bf16 hi/lo normalize + MFMA-fragment pack (L1..L4) ----------------
__global__ __launch_bounds__(BLK) void wnorm_pack_bf16(
    const float* __restrict__ W, short* __restrict__ Cpk, short* __restrict__ Tpk,
    int Cout, int Cin)
{
    int o = blockIdx.x;
    int asz = Cin * 16;
    const float* w = W + (size_t)o * asz;
    float s = 0.f;
    for (int i = threadIdx.x; i < asz; i += BLK) { float v = w[i]; s = fmaf(v, v, s); }
    float tot = blk_reduce(s);
    float inv = 1.0f / (sqrtf(tot) + 1e-12f);
    size_t cTot = (size_t)Cout * asz;
    size_t parStride = (size_t)Cout * 4 * Cin;
    size_t tTot = 4 * parStride;
    for (int i = threadIdx.x; i < asz; i += BLK) {
        float v = w[i] * inv;
        unsigned short hb = f2bf(v);
        unsigned short lb = f2bf(v - bf2f(hb));
        size_t cidx = ((size_t)(i >> 3)) * (Cout * 8) + o * 8 + (i & 7);
        Cpk[cidx] = (short)hb;
        Cpk[cTot + cidx] = (short)lb;
        int c = i >> 4, tap = i & 15, kh = tap >> 2, kw = tap & 3;
        int par = (1 - (kh & 1)) * 2 + (1 - (kw & 1));
        int tt = ((kh >> 1) << 1) | (kw >> 1);
        int q = o * 4 + tt;
        size_t tidx = (size_t)par * parStride + ((size_t)(q >> 3)) * (Cin * 8) + c * 8 + (q & 7);
        Tpk[tidx] = (short)hb;
        Tpk[tTot + tidx] = (short)lb;
    }
}

// ---------------- XCD-aware bijective swizzle ----------------
__device__ inline void xcd_remap(int& bx, int& by, int& bz) {
    int nx = gridDim.x, ny = gridDim.y;
    int nwg = nx * ny * gridDim.z;
    int orig = blockIdx.x + nx * (blockIdx.y + ny * blockIdx.z);
    int q8 = nwg >> 3, r8 = nwg & 7, xcd = orig & 7, sidx = orig >> 3;
    int w = (xcd < r8 ? xcd * (q8 + 1) : r8 * (q8 + 1) + (xcd - r8) * q8) + sidx;
    bx = w % nx; int t = w / nx; by = t % ny; bz = t / ny;
}

// ---------------- bf16x3 MFMA implicit-GEMM forward conv (K=4,S=2,P=1) ----------------
// 64-K per barrier pair, reg-prefetched (T14). kchunk % 64 == 0 required.
__global__ __launch_bounds__(BLK) void conv_gemm_bf16(
    const short* __restrict__ Wpk, const float* __restrict__ x,
    const float* __restrict__ yin, float* __restrict__ out,
    int M, int Cx, int Hx, int Wx, int Hout, int Wout,
    int kchunk, int emode)
{
    __shared__ __align__(16) short Wh[8][64][8];
    __shared__ __align__(16) short Wo_[8][64][8];
    __shared__ __align__(16) short Xh[8][64][8];
    __shared__ __align__(16) short Xo[8][64][8];
    int bx, by, bz; xcd_remap(bx, by, bz);
    int tid = threadIdx.x, lane = tid & 63, wid = tid >> 6;
    int HW = Hout * Wout, HWx = Hx * Wx;
    int pbase = bx * 64, m0 = by * 64, kb = bz * kchunk;
    size_t loOff = (size_t)Cx * 16 * M;

    int spl = tid & 63, skb = tid >> 6;
    int sp = pbase + spl;
    int sn = sp / HW; int srr = sp - sn * HW;
    int sho = srr / Wout, swo = srr - sho * Wout;
    const float* xs = x + (size_t)sn * Cx * HWx;
    int h0 = sho * 2 - 1, w0 = swo * 2 - 1;

    int t16 = (skb & 1) * 8;
    int offs[8]; bool valt[8];
    #pragma unroll
    for (int jj = 0; jj < 8; ++jj) {
        int tap = t16 + jj;
        int kh = tap >> 2, kw = tap & 3;
        int h = h0 + kh, w = w0 + kw;
        valt[jj] = ((unsigned)h < (unsigned)Hx) && ((unsigned)w < (unsigned)Wx);
        offs[jj] = h * Wx + w;
    }
    const float* xc = xs + ((size_t)(kb >> 4) + (skb >> 1)) * HWx;

    // prologue gather (both halves of first 64-K step)
    float4 w_hi[2], w_lo[2];
    float g[2][8];
    #pragma unroll
    for (int h = 0; h < 2; ++h) {
        size_t so = ((size_t)(((kb + 32 * h) >> 3) + skb)) * (M * 8) + (size_t)m0 * 8 + spl * 8;
        w_hi[h] = *(const float4*)(Wpk + so);
        w_lo[h] = *(const float4*)(Wpk + loOff + so);
        #pragma unroll
        for (int jj = 0; jj < 8; ++jj)
            g[h][jj] = valt[jj] ? xc[h * 2 * HWx + offs[jj]] : 0.f;
    }
    xc += 4 * HWx;

    f32x4 acc[4] = {};
    for (int k0 = kb; k0 < kb + kchunk; k0 += 64) {
        // convert + store both halves into LDS
        #pragma unroll
        for (int h = 0; h < 2; ++h) {
            *(float4*)(&Wh[h * 4 + skb][spl][0])  = w_hi[h];
            *(float4*)(&Wo_[h * 4 + skb][spl][0]) = w_lo[h];
            union { short s8[8]; float4 f; } uh, ul;
            #pragma unroll
            for (int jj = 0; jj < 8; ++jj) {
                float gg = g[h][jj];
                unsigned short hb = (unsigned short)(__float_as_uint(gg) >> 16);
                uh.s8[jj] = (short)hb;
                ul.s8[jj] = (short)f2bf(gg - bf2f(hb));
            }
            *(float4*)(&Xh[h * 4 + skb][spl][0]) = uh.f;
            *(float4*)(&Xo[h * 4 + skb][spl][0]) = ul.f;
        }
        __syncthreads();
        // prefetch next 64-K (overlaps MFMA + barrier)
        if (k0 + 64 < kb + kchunk) {
            #pragma unroll
            for (int h = 0; h < 2; ++h) {
                size_t so2 = ((size_t)(((k0 + 64 + 32 * h) >> 3) + skb)) * (M * 8)
                           + (size_t)m0 * 8 + spl * 8;
                w_hi[h] = *(const float4*)(Wpk + so2);
                w_lo[h] = *(const float4*)(Wpk + loOff + so2);
                #pragma unroll
                for (int jj = 0; jj < 8; ++jj)
                    g[h][jj] = valt[jj] ? xc[h * 2 * HWx + offs[jj]] : 0.f;
            }
            xc += 4 * HWx;
        }
        #pragma unroll
        for (int half = 0; half < 2; ++half) {
            bf16x8 ah = *(const bf16x8*)(&Wh[half * 4 + (lane >> 4)][wid * 16 + (lane & 15)][0]);
            bf16x8 al = *(const bf16x8*)(&Wo_[half * 4 + (lane >> 4)][wid * 16 + (lane & 15)][0]);
            #pragma unroll
            for (int nf = 0; nf < 4; ++nf) {
                bf16x8 bh = *(const bf16x8*)(&Xh[half * 4 + (lane >> 4)][nf * 16 + (lane & 15)][0]);
                bf16x8 bl = *(const bf16x8*)(&Xo[half * 4 + (lane >> 4)][nf * 16 + (lane & 15)][0]);
                acc[nf] = __builtin_amdgcn_mfma_f32_16x16x32_bf16(al, bh, acc[nf], 0, 0, 0);
                acc[nf] = __builtin_amdgcn_mfma_f32_16x16x32_bf16(ah, bl, acc[nf], 0, 0, 0);
                acc[nf] = __builtin_amdgcn_mfma_f32_16x16x32_bf16(ah, bh, acc[nf], 0, 0, 0);
            }
        }
        __syncthreads();
    }
    int colp = lane & 15, rquad = lane >> 4;
    #pragma unroll
    for (int nf = 0; nf < 4; ++nf) {
        int p = pbase + nf * 16 + colp;
        int n = p / HW; int rr = p - n * HW;
        int ho = rr / Wout, wo = rr - ho * Wout;
        #pragma unroll
        for (int r = 0; r < 4; ++r) {
            int m = m0 + wid * 16 + rquad * 4 + r;
            size_t idx = (((size_t)n * M + m) * Hout + ho) * Wout + wo;
            float v = acc[nf][r];
            if (emode == 0)      out[idx] = fmaxf(MU_F * v - THR_F, 0.f);
            else if (emode == 1) out[idx] = fmaxf(yin[idx] + MU_F * v - THR_F, 0.f);
            else                 atomicAdd(&out[idx], v);
        }
    }
}

// ---------------- bf16x3 MFMA implicit-GEMM transpose conv (64-K per barrier pair) ----------------
__global__ __launch_bounds__(BLK) void convt_gemm_bf16(
    const short* __restrict__ Wpk, const float* __restrict__ z,
    const float* __restrict__ aux, float* __restrict__ out,
    int M, int Cz, int Hz, int Wz, int Ho, int Wo, int emode, int SK)
{
    __shared__ __align__(16) short Wh[8][64][8];
    __shared__ __align__(16) short Wo_[8][64][8];
    __shared__ __align__(16) short Xh[8][64][8];
    __shared__ __align__(16) short Xo[8][64][8];
    int bx, by, bz; xcd_remap(bx, by, bz);
    int tid = threadIdx.x, lane = tid & 63, wid = tid >> 6;
    int par = bz / SK, chunk = bz - par * SK;
    int hbit = par >> 1, wbit = par & 1;
    int czs = Cz / SK;
    int qb = chunk * czs * 4;
    size_t parS = (size_t)Cz * 4 * M;
    const short* Wp = Wpk + (size_t)par * parS;
    size_t loOff = 4 * parS;
    int Hc = Ho >> 1, Wc = Wo >> 1, HWc = Hc * Wc;
    int pbase = bx * 64, m0 = by * 64;

    int spl = tid & 63, skb = tid >> 6;
    int sp = pbase + spl;
    int sn = sp / HWc; int srr = sp - sn * HWc;
    int shc = srr / Wc, swc = srr - shc * Wc;
    int HWz = Hz * Wz;
    const float* zs = z + (size_t)sn * Cz * HWz;

    int offt[4]; bool valt[4];
    #pragma unroll
    for (int t = 0; t < 4; ++t) {
        int ti = t >> 1, tj = t & 1;
        int hn = shc + hbit - ti, wn = swc + wbit - tj;
        valt[t] = ((unsigned)hn < (unsigned)Hz) && ((unsigned)wn < (unsigned)Wz);
        offt[t] = hn * Wz + wn;
    }
    const float* zc = zs + ((size_t)(qb >> 2) + skb * 2) * HWz;

    // prologue gather (both halves)
    float4 w_hi[2], w_lo[2];
    float g[2][8];
    #pragma unroll
    for (int h = 0; h < 2; ++h) {
        size_t so = ((size_t)(((qb + 32 * h) >> 3) + skb)) * (M * 8) + (size_t)m0 * 8 + spl * 8;
        w_hi[h] = *(const float4*)(Wp + so);
        w_lo[h] = *(const float4*)(Wp + loOff + so);
        #pragma unroll
        for (int jj = 0; jj < 8; ++jj) {
            int t = jj & 3;
            g[h][jj] = valt[t] ? zc[(h * 8 + (jj >> 2)) * HWz + offt[t]] : 0.f;
        }
    }
    zc += 16 * HWz;

    f32x4 acc[4] = {};
    for (int q0 = qb; q0 < qb + czs * 4; q0 += 64) {
        #pragma unroll
        for (int h = 0; h < 2; ++h) {
            *(float4*)(&Wh[h * 4 + skb][spl][0])  = w_hi[h];
            *(float4*)(&Wo_[h * 4 + skb][spl][0]) = w_lo[h];
            union { short s8[8]; float4 f; } uh, ul;
            #pragma unroll
            for (int jj = 0; jj < 8; ++jj) {
                float gg = g[h][jj];
                unsigned short hb = (unsigned short)(__float_as_uint(gg) >> 16);
                uh.s8[jj] = (short)hb;
                ul.s8[jj] = (short)f2bf(gg - bf2f(hb));
            }
            *(float4*)(&Xh[h * 4 + skb][spl][0]) = uh.f;
            *(float4*)(&Xo[h * 4 + skb][spl][0]) = ul.f;
        }
        __syncthreads();
        if (q0 + 64 < qb + czs * 4) {
            #pragma unroll
            for (int h = 0; h < 2; ++h) {
                size_t so2 = ((size_t)(((q0 + 64 + 32 * h) >> 3) + skb)) * (M * 8)
                           + (size_t)m0 * 8 + spl * 8;
                w_hi[h] = *(const float4*)(Wp + so2);
                w_lo[h] = *(const float4*)(Wp + loOff + so2);
                #pragma unroll
                for (int jj = 0; jj < 8; ++jj) {
                    int t = jj & 3;
                    g[h][jj] = valt[t] ? zc[(h * 8 + (jj >> 2)) * HWz + offt[t]] : 0.f;
                }
            }
            zc += 16 * HWz;
        }
        #pragma unroll
        for (int half = 0; half < 2; ++half) {
            bf16x8 ah = *(const bf16x8*)(&Wh[half * 4 + (lane >> 4)][wid * 16 + (lane & 15)][0]);
            bf16x8 al = *(const bf16x8*)(&Wo_[half * 4 + (lane >> 4)][wid * 16 + (lane & 15)][0]);
            #pragma unroll
            for (int nf = 0; nf < 4; ++nf) {
                bf16x8 bh = *(const bf16x8*)(&Xh[half * 4 + (lane >> 4)][nf * 16 + (lane & 15)][0]);
                bf16x8 bl = *(const bf16x8*)(&Xo[half * 4 + (lane >> 4)][nf * 16 + (lane & 15)][0]);
                acc[nf] = __builtin_amdgcn_mfma_f32_16x16x32_bf16(al, bh, acc[nf], 0, 0, 0);
                acc[nf] = __builtin_amdgcn_mfma_f32_16x16x32_bf16(ah, bl, acc[nf], 0, 0, 0);
                acc[nf] = __builtin_amdgcn_mfma_f32_16x16x32_bf16(ah, bh, acc[nf], 0, 0, 0);
            }
        }
        __syncthreads();
    }
    int colp = lane & 15, rquad = lane >> 4;
    #pragma unroll
    for (int nf = 0; nf < 4; ++nf) {
        int p = pbase + nf * 16 + colp;
        int n = p / HWc; int rr = p - n * HWc;
        int hc = rr / Wc, wc = rr - hc * Wc;
        int ho = 2 * hc + hbit, wo = 2 * wc + wbit;
        #pragma unroll
        for (int r = 0; r < 4; ++r) {
            int m = m0 + wid * 16 + rquad * 4 + r;
            size_t idx = (((size_t)n * M + m) * Ho + ho) * Wo + wo;
            float v = acc[nf][r];
            if (emode == 0)      out[idx] = aux[idx] - v;
            else if (emode == 1) out[idx] = v;
            else                 atomicAdd(&out[idx], v);
        }
    }
}

// ---------------- fp32 implicit-GEMM forward conv (L0, L5) ----------------
template <int KK, int Kk, int S, int P>
__global__ __launch_bounds__(BLK) void conv_gemm(
    const float* __restrict__ Wp, const float* __restrict__ x,
    const float* __restrict__ yin, float* __restrict__ out,
    int M, int Ktot, int Cx, int Hx, int Wx, int Hout, int Wout,
    int kchunk, int emode)
{
    __shared__ float Wt[16][64];
    __shared__ float Xt[16][64];
    int tid = threadIdx.x, tx = tid & 15, ty = tid >> 4;
    int HW = Hout * Wout, HWx = Hx * Wx;
    int pbase = blockIdx.x * 64 + tx * 4;
    int n_[4], ho_[4], wo_[4];
    const float* xb_[4];
    #pragma unroll
    for (int j = 0; j < 4; ++j) {
        int p = pbase + j; int n = p / HW; int r = p - n * HW;
        int ho = r / Wout; int wo = r - ho * Wout;
        n_[j] = n; ho_[j] = ho; wo_[j] = wo;
        xb_[j] = x + (size_t)n * Cx * HWx;
    }
    int m0 = blockIdx.y * 64;
    int kb = blockIdx.z * kchunk, ke = kb + kchunk;
    if (ke > Ktot) ke = Ktot;
    float acc[4][4] = {};
    for (int k0 = kb; k0 < ke; k0 += 16) {
        int kr = k0 + ty;
        *(float4*)&Wt[ty][tx * 4] = *(const float4*)&Wp[(size_t)kr * M + m0 + tx * 4];
        int ci = kr / KK; int t = kr - ci * KK; int kh = t / Kk; int kw = t - kh * Kk;
        int cio = ci * HWx;
        float g[4];
        #pragma unroll
        for (int j = 0; j < 4; ++j) {
            int h = ho_[j] * S - P + kh, w = wo_[j] * S - P + kw;
            g[j] = ((unsigned)h < (unsigned)Hx && (unsigned)w < (unsigned)Wx)
                 ? xb_[j][cio + h * Wx + w] : 0.f;
        }
        *(float4*)&Xt[ty][tx * 4] = make_float4(g[0], g[1], g[2], g[3]);
        __syncthreads();
        #pragma unroll
        for (int kk = 0; kk < 16; ++kk) {
            float4 a = *(float4*)&Wt[kk][ty * 4];
            float4 b = *(float4*)&Xt[kk][tx * 4];
            float aa[4] = {a.x, a.y, a.z, a.w};
            float bb[4] = {b.x, b.y, b.z, b.w};
            #pragma unroll
            for (int i = 0; i < 4; ++i)
                #pragma unroll
                for (int j = 0; j < 4; ++j)
                    acc[i][j] = fmaf(aa[i], bb[j], acc[i][j]);
        }
        __syncthreads();
    }
    #pragma unroll
    for (int i = 0; i < 4; ++i) {
        int m = m0 + ty * 4 + i;
        #pragma unroll
        for (int j = 0; j < 4; ++j) {
            size_t idx = (((size_t)n_[j] * M + m) * Hout + ho_[j]) * Wout + wo_[j];
            float v = acc[i][j];
            if (emode == 0)      out[idx] = fmaxf(MU_F * v - THR_F, 0.f);
            else if (emode == 1) out[idx] = fmaxf(yin[idx] + MU_F * v - THR_F, 0.f);
            else                 atomicAdd(&out[idx], v);
        }
    }
}

// ---------------- 1x1-source transpose conv as plain GEMM (L5) ----------------
__global__ __launch_bounds__(BLK) void outer_gemm(
    const float* __restrict__ Wp, const float* __restrict__ zin,
    const float* __restrict__ aux, float* __restrict__ out,
    int M, int Kz, int emode)
{
    __shared__ float Wt[16][64];
    __shared__ float Xt[16][64];
    int tid = threadIdx.x, tx = tid & 15, ty = tid >> 4;
    int m0 = blockIdx.y * 64;
    float acc[4][4] = {};
    for (int k0 = 0; k0 < Kz; k0 += 16) {
        int kr = k0 + ty;
        *(float4*)&Wt[ty][tx * 4] = *(const float4*)&Wp[(size_t)kr * M + m0 + tx * 4];
        float g[4];
        #pragma unroll
        for (int j = 0; j < 4; ++j) g[j] = zin[(size_t)(tx * 4 + j) * Kz + kr];
        *(float4*)&Xt[ty][tx * 4] = make_float4(g[0], g[1], g[2], g[3]);
        __syncthreads();
        #pragma unroll
        for (int kk = 0; kk < 16; ++kk) {
            float4 a = *(float4*)&Wt[kk][ty * 4];
            float4 b = *(float4*)&Xt[kk][tx * 4];
            float aa[4] = {a.x, a.y, a.z, a.w};
            float bb[4] = {b.x, b.y, b.z, b.w};
            #pragma unroll
            for (int i = 0; i < 4; ++i)
                #pragma unroll
                for (int j = 0; j < 4; ++j)
                    acc[i][j] = fmaf(aa[i], bb[j], acc[i][j]);
        }
        __syncthreads();
    }
    #pragma unroll
    for (int i = 0; i < 4; ++i) {
        int m = m0 + ty * 4 + i;
        #pragma unroll
        for (int j = 0; j < 4; ++j) {
            int n = tx * 4 + j;
            size_t idx = (size_t)n * M + m;
            float v = acc[i][j];
            out[idx] = (emode == 0) ? (aux[idx] - v) : v;
        }
    }
}

// ---------------- M=3 transpose conv (image space, fp32) ----------------
__global__ __launch_bounds__(BLK) void convt_m3(
    const float* __restrict__ Wkc0, const float* __restrict__ z,
    const float* __restrict__ aux, float* __restrict__ out,
    int Cz, int Hz, int Wz, int Ho, int Wo, int emode)
{
    __shared__ float Wl[64 * 4 * 3];
    int tid = threadIdx.x;
    int hbit = blockIdx.z >> 1, wbit = blockIdx.z & 1;
    int khp = 1 - hbit, kwp = 1 - wbit;
    int Ktot = Cz * 4;
    for (int kidx = tid; kidx < Ktot; kidx += BLK) {
        int cz = kidx >> 2, t = kidx & 3, ti = t >> 1, tj = t & 1;
        int tap = (khp + 2 * ti) * 4 + (kwp + 2 * tj);
        Wl[kidx * 3 + 0] = Wkc0[(0 * 16 + tap) * 64 + cz];
        Wl[kidx * 3 + 1] = Wkc0[(1 * 16 + tap) * 64 + cz];
        Wl[kidx * 3 + 2] = Wkc0[(2 * 16 + tap) * 64 + cz];
    }
    __syncthreads();
    int Hc = Ho >> 1, Wc = Wo >> 1, HWc = Hc * Wc;
    int p = blockIdx.x * BLK + tid;
    int n = p / HWc, r = p - n * HWc, hc = r / Wc, wc = r - (r / Wc) * Wc;
    const float* zb = z + (size_t)n * Cz * Hz * Wz;
    int offs[4]; bool val[4];
    #pragma unroll
    for (int t = 0; t < 4; ++t) {
        int ti = t >> 1, tj = t & 1;
        int hn = hc + hbit - ti, wn = wc + wbit - tj;
        val[t] = ((unsigned)hn < (unsigned)Hz) && ((unsigned)wn < (unsigned)Wz);
        offs[t] = hn * Wz + wn;
    }
    float a0 = 0.f, a1 = 0.f, a2 = 0.f;
    int HWz = Hz * Wz;
    for (int cz = 0; cz < Cz; ++cz) {
        const float* base = zb + cz * HWz;
        #pragma unroll
        for (int t = 0; t < 4; ++t) {
            float g = val[t] ? base[offs[t]] : 0.f;
            int wi = (cz * 4 + t) * 3;
            a0 = fmaf(g, Wl[wi + 0], a0);
            a1 = fmaf(g, Wl[wi + 1], a1);
            a2 = fmaf(g, Wl[wi + 2], a2);
        }
    }
    int ho = 2 * hc + hbit, wo = 2 * wc + wbit;
    #pragma unroll
    for (int u = 0; u < 3; ++u) {
        float v = (u == 0) ? a0 : (u == 1) ? a1 : a2;
        size_t idx = (((size_t)n * 3 + u) * Ho + ho) * Wo + wo;
        out[idx] = (emode == 0) ? (aux[idx] - v) : tanhf(v);
    }
}

// ---------------- vectorized epilogues / elementwise (n % 4 == 0) ----------------
__global__ __launch_bounds__(BLK) void shrink_epi_v4(
    const float* __restrict__ p, const float* __restrict__ y,
    float* __restrict__ o, int n4, int mode)
{
    int i = blockIdx.x * BLK + threadIdx.x;
    if (i >= n4) return;
    float4 pv = ((const float4*)p)[i];
    float4 r;
    if (mode == 1) {
        float4 yv = ((const float4*)y)[i];
        r.x = fmaxf(yv.x + MU_F * pv.x - THR_F, 0.f);
        r.y = fmaxf(yv.y + MU_F * pv.y - THR_F, 0.f);
        r.z = fmaxf(yv.z + MU_F * pv.z - THR_F, 0.f);
        r.w = fmaxf(yv.w + MU_F * pv.w - THR_F, 0.f);
    } else {
        r.x = fmaxf(MU_F * pv.x - THR_F, 0.f);
        r.y = fmaxf(MU_F * pv.y - THR_F, 0.f);
        r.z = fmaxf(MU_F * pv.z - THR_F, 0.f);
        r.w = fmaxf(MU_F * pv.w - THR_F, 0.f);
    }
    ((float4*)o)[i] = r;
}

__global__ __launch_bounds__(BLK) void res_epi_v4(
    const float* __restrict__ aux, const float* __restrict__ acc,
    float* __restrict__ o, int n4)
{
    int i = blockIdx.x * BLK + threadIdx.x;
    if (i >= n4) return;
    float4 a = ((const float4*)aux)[i];
    float4 b = ((const float4*)acc)[i];
    ((float4*)o)[i] = make_float4(a.x - b.x, a.y - b.y, a.z - b.z, a.w - b.w);
}

__global__ __launch_bounds__(BLK) void y_update_v4(
    const float* __restrict__ z, const float* __restrict__ zo,
    float* __restrict__ y, int n4, float c)
{
    int i = blockIdx.x * BLK + threadIdx.x;
    if (i >= n4) return;
    float4 zv = ((const float4*)z)[i];
    float4 ov = ((const float4*)zo)[i];
    ((float4*)y)[i] = make_float4(
        fmaf(c, zv.x - ov.x, zv.x), fmaf(c, zv.y - ov.y, zv.y),
        fmaf(c, zv.z - ov.z, zv.z), fmaf(c, zv.w - ov.w, zv.w));
}

// ---------------- two-stage BN stats ----------------
__global__ __launch_bounds__(BLK) void bn_stats_part(
    const float* __restrict__ x, float* __restrict__ stats,
    int N, int C, int HW, int nblk)
{
    int c = blockIdx.x, b = blockIdx.y;
    int cnt = N * HW;
    float s = 0.f, s2 = 0.f;
    for (int i = b * BLK + threadIdx.x; i < cnt; i += nblk * BLK) {
        int n = i / HW, hw = i - n * HW;
        float v = x[((size_t)n * C + c) * HW + hw];
        s += v; s2 = fmaf(v, v, s2);
    }
    float ts  = blk_reduce(s);
    float ts2 = blk_reduce(s2);
    if (threadIdx.x == 0) {
        atomicAdd(&stats[c], ts);
        atomicAdd(&stats[C + c], ts2);
    }
}
__global__ __launch_bounds__(BLK) void bn_finalize(
    const float* __restrict__ stats, float* __restrict__ mean,
    float* __restrict__ rstd, int C, int cnt)
{
    int c = blockIdx.x * BLK + threadIdx.x;
    if (c >= C) return;
    float m = stats[c] / cnt;
    float var = stats[C + c] / cnt - m * m;
    mean[c] = m;
    rstd[c] = rsqrtf(var + 1e-5f);
}

// ---------------- BN apply + activation, vectorized ----------------
__global__ __launch_bounds__(BLK) void bn_act_v4(
    const float* __restrict__ x, const float* __restrict__ mean,
    const float* __restrict__ rstd, float* __restrict__ out,
    int n4, int C, int HW, int use_bn, int act)
{
    int i = blockIdx.x * BLK + threadIdx.x;
    if (i >= n4) return;
    float4 v = ((const float4*)x)[i];
    float e[4] = {v.x, v.y, v.z, v.w};
    int base = i * 4;
    #pragma unroll
    for (int j = 0; j < 4; ++j) {
        float t = e[j];
        if (use_bn) { int c = ((base + j) / HW) % C; t = (t - mean[c]) * rstd[c]; }
        e[j] = (act == 0) ? ((t >= 0.f) ? t : 0.2f * t) : fmaxf(t, 0.f);
    }
    ((float4*)out)[i] = make_float4(e[0], e[1], e[2], e[3]);
}

// ---------------- per-row L2 normalize ----------------
__global__ __launch_bounds__(128) void rownorm_kernel(
    const float* __restrict__ z, float* __restrict__ out, float* __restrict__ zvec)
{
    __shared__ float sh[128];
    int r = blockIdx.x, tid = threadIdx.x;
    float v = z[r * 128 + tid];
    sh[tid] = v * v;
    __syncthreads();
    #pragma unroll
    for (int s = 64; s > 0; s >>= 1) {
        if (tid < s) sh[tid] += sh[tid + s];
        __syncthreads();
    }
    float nrm = fmaxf(sqrtf(sh[0]), 1e-12f);
    float o = v / nrm;
    out[r * 128 + tid] = o;
    zvec[r * 128 + tid] = o;
}

static inline int gdiv(int a, int b) { return (a + b - 1) / b; }

extern "C" void kernel_launch(void* const* d_in, const int* in_sizes, int n_in,
                              void* d_out, int out_size, void* d_ws, size_t ws_size,
                              hipStream_t stream)
{
    const float* x = (const float*)d_in[0];
    const float* W[6];
    for (int i = 0; i < 6; ++i) W[i] = (const float*)d_in[1 + i];
    float* ws  = (float*)d_ws;
    float* out = (float*)d_out;

    const int Cin[6]  = {3, 64, 128, 256, 512, 1024};
    const int Cout[6] = {64, 128, 256, 512, 1024, 128};
    const int Hin[6]  = {96, 48, 24, 12, 6, 3};
    const int Hout[6] = {48, 24, 12, 6, 3, 1};
    const int N = 64;
    const int SKc[6] = {1, 1, 2, 4, 8, 1};
    const int SKt[6] = {1, 1, 1, 2, 4, 1};

    // ---- workspace layout: ~66.53M floats = 253.8 MB ----
    size_t off = 0;
    float* Wkc0 = ws + off; off += 3072;
    float* Wkc5 = ws + off; off += 1179648;
    float* Wn5  = ws + off; off += 1179648;
    const size_t csz[5] = {0, 131072, 524288, 2097152, 8388608};
    short* Cpk[5]; short* Tpk[5];
    {
        short* sbase = (short*)(ws + off);
        size_t soff = 0;
        for (int L = 1; L < 5; ++L) { Cpk[L] = sbase + soff; soff += 2 * csz[L]; }
        for (int L = 1; L < 5; ++L) { Tpk[L] = sbase + soff; soff += 2 * csz[L]; }
        off += soff / 2;
    }
    const size_t POOL = 30081024;
    float* pool = ws + off; off += POOL;
    float* xb   = ws + off; off += 9437184;
    float* mean = ws + off; off += 1024;
    float* rstd = ws + off; off += 1024;
    float* stats= ws + off; off += 2048;
    float* zvec = ws + off; off += 8192;
    float* pbuf = ws + off; off += 2359296;

    // ---- normalize + pack dictionaries ----
    wnorm_pack<<<64, BLK, 0, stream>>>(W[0], Wkc0, nullptr, 64, 48);
    for (int L = 1; L < 5; ++L)
        wnorm_pack_bf16<<<Cout[L], BLK, 0, stream>>>(W[L], Cpk[L], Tpk[L], Cout[L], Cin[L]);
    wnorm_pack<<<128, BLK, 0, stream>>>(W[5], Wkc5, Wn5, 128, 9216);

    // ---- FISTA momentum coefficients ----
    double td = 1.0; float cc[3];
    for (int i = 0; i < 3; ++i) {
        double tn = (1.0 + sqrt(1.0 + 4.0 * td * td)) * 0.5;
        cc[i] = (float)((td - 1.0) / tn);
        td = tn;
    }

    auto run_bn_stats = [&](const float* src, int C, int HW) {
        int cnt = N * HW;
        int nblk = 2048 / C; if (nblk < 1) nblk = 1;
        int maxb = gdiv(cnt, BLK); if (nblk > maxb) nblk = maxb;
        hipMemsetAsync(stats, 0, 2 * C * sizeof(float), stream);
        bn_stats_part<<<dim3(C, nblk), BLK, 0, stream>>>(src, stats, N, C, HW, nblk);
        bn_finalize<<<gdiv(C, BLK), BLK, 0, stream>>>(stats, mean, rstd, C, cnt);
    };

    const float* in = x;
    for (int L = 0; L < 6; ++L) {
        int zTot = N * Cout[L] * Hout[L] * Hout[L];
        int xTot = N * Cin[L] * Hin[L] * Hin[L];
        int npix = N * Hout[L] * Hout[L];
        dim3 ge4(gdiv(zTot / 4, BLK));
        dim3 gr4(gdiv(xTot / 4, BLK));

        float* zA = pool;
        float* zB = pool + (size_t)zTot;
        float* yb = pool + (size_t)2 * zTot;
        float* rb = pool + (size_t)3 * zTot;

        auto launch_conv = [&](const float* src, const float* y, float* dst, int mode) {
            if (L == 5) {
                hipMemsetAsync(pbuf, 0, (size_t)zTot * 4, stream);
                conv_gemm<9, 3, 1, 0><<<dim3(1, 2, 72), BLK, 0, stream>>>(Wkc5, src,
                    nullptr, pbuf, 128, 9216, 1024, 3, 3, 1, 1, 128, 2);
                shrink_epi_v4<<<gdiv(zTot / 4, BLK), BLK, 0, stream>>>(pbuf, y, dst, zTot / 4, mode);
            } else if (L == 0) {
                conv_gemm<16, 4, 2, 1><<<dim3(npix / 64, 1), BLK, 0, stream>>>(
                    Wkc0, src, y, dst, 64, 48, 3, 96, 96, 48, 48, 48, mode);
            } else if (SKc[L] == 1) {
                conv_gemm_bf16<<<dim3(npix / 64, Cout[L] / 64), BLK, 0, stream>>>(
                    Cpk[L], src, y, dst, Cout[L], Cin[L], Hin[L], Hin[L],
                    Hout[L], Hout[L], Cin[L] * 16, mode);
            } else {
                int sk = SKc[L];
                hipMemsetAsync(pbuf, 0, (size_t)zTot * 4, stream);
                conv_gemm_bf16<<<dim3(npix / 64, Cout[L] / 64, sk), BLK, 0, stream>>>(
                    Cpk[L], src, nullptr, pbuf, Cout[L], Cin[L], Hin[L], Hin[L],
                    Hout[L], Hout[L], Cin[L] * 16 / sk, 2);
                shrink_epi_v4<<<gdiv(zTot / 4, BLK), BLK, 0, stream>>>(pbuf, y, dst, zTot / 4, mode);
            }
        };

        // z0 = shrink(MU * conv(in))
        launch_conv(in, nullptr, zA, 0);

        float* z = zA; float* zo = zB;
        for (int it = 0; it < 3; ++it) {
            const float* ybp;
            if (it == 0) {
                ybp = z;                 // c = 0 -> y == z
            } else {
                y_update_v4<<<ge4, BLK, 0, stream>>>(z, zo, yb, zTot / 4, cc[it]);
                ybp = yb;
            }
            // r = in - convT(y)
            if (L == 0) {
                convt_m3<<<dim3(N * 48 * 48 / BLK, 1, 4), BLK, 0, stream>>>(
                    Wkc0, ybp, in, rb, 64, 48, 48, 96, 96, 0);
            } else if (L < 5) {
                int xpixc = N * (Hin[L] / 2) * (Hin[L] / 2);
                int sk = SKt[L];
                if (sk == 1) {
                    convt_gemm_bf16<<<dim3(xpixc / 64, Cin[L] / 64, 4), BLK, 0, stream>>>(
                        Tpk[L], ybp, in, rb, Cin[L], Cout[L], Hout[L], Hout[L],
                        Hin[L], Hin[L], 0, 1);
                } else {
                    hipMemsetAsync(rb, 0, (size_t)xTot * 4, stream);
                    convt_gemm_bf16<<<dim3(xpixc / 64, Cin[L] / 64, 4 * sk), BLK, 0, stream>>>(
                        Tpk[L], ybp, nullptr, rb, Cin[L], Cout[L], Hout[L], Hout[L],
                        Hin[L], Hin[L], 2, sk);
                    res_epi_v4<<<gr4, BLK, 0, stream>>>(in, rb, rb, xTot / 4);
                }
            } else {
                outer_gemm<<<dim3(1, 144), BLK, 0, stream>>>(Wn5, ybp, in, rb, 9216, 128, 0);
            }
            // z_new = shrink(y + MU*conv(r))
            launch_conv(rb, ybp, zo, 1);
            float* tmp = z; z = zo; zo = tmp;
        }

        int HW = Hout[L] * Hout[L];
        if (L == 0) {
            bn_act_v4<<<ge4, BLK, 0, stream>>>(z, nullptr, nullptr, xb, zTot / 4, Cout[L], HW, 0, 0);
            in = xb;
        } else if (L < 5) {
            run_bn_stats(z, Cout[L], HW);
            bn_act_v4<<<ge4, BLK, 0, stream>>>(z, mean, rstd, xb, zTot / 4, Cout[L], HW, 1, 0);
            in = xb;
        } else {
            rownorm_kernel<<<64, 128, 0, stream>>>(z, out, zvec);
        }
    }

    // ---- decoder (bf16x3 convT stages, fp32 elsewhere) ----
    float* zA = pool;
    float* zB = pool + 9437184;
    {
        int oT = N * 1024 * 9;
        outer_gemm<<<dim3(1, 144), BLK, 0, stream>>>(Wn5, zvec, nullptr, zA, 9216, 128, 1);
        run_bn_stats(zA, 1024, 9);
        bn_act_v4<<<gdiv(oT / 4, BLK), BLK, 0, stream>>>(zA, mean, rstd, zB, oT / 4, 1024, 9, 1, 1);
    }
    float* cur = zB;
    for (int i = 4; i >= 1; --i) {
        int oT = N * Cin[i] * Hin[i] * Hin[i];
        int xpixc = N * (Hin[i] / 2) * (Hin[i] / 2);
        int sk = SKt[i];
        if (sk == 1) {
            convt_gemm_bf16<<<dim3(xpixc / 64, Cin[i] / 64, 4), BLK, 0, stream>>>(
                Tpk[i], cur, nullptr, zA, Cin[i], Cout[i], Hout[i], Hout[i],
                Hin[i], Hin[i], 1, 1);
        } else {
            hipMemsetAsync(zA, 0, (size_t)oT * 4, stream);
            convt_gemm_bf16<<<dim3(xpixc / 64, Cin[i] / 64, 4 * sk), BLK, 0, stream>>>(
                Tpk[i], cur, nullptr, zA, Cin[i], Cout[i], Hout[i], Hout[i],
                Hin[i], Hin[i], 2, sk);
        }
        run_bn_stats(zA, Cin[i], Hin[i] * Hin[i]);
        bn_act_v4<<<gdiv(oT / 4, BLK), BLK, 0, stream>>>(zA, mean, rstd, zB, oT / 4,
            Cin[i], Hin[i] * Hin[i], 1, 1);
        cur = zB;
    }
    convt_m3<<<dim3(N * 48 * 48 / BLK, 1, 4), BLK, 0, stream>>>(
        Wkc0, cur, nullptr, out + 8192, 64, 48, 48, 96, 96, 2);
}

// Round 13
// 3802.016 us; speedup vs baseline: 1.4649x; 1.4649x over previous
//
#include <hip/hip_runtime.h>
#include <math.h>

#define BLK 256
static constexpr float MU_F  = 0.1f;
static constexpr float THR_F = 0.01f;

typedef __attribute__((ext_vector_type(8))) short bf16x8;
typedef __attribute__((ext_vector_type(4))) float f32x4;

__device__ inline unsigned short f2bf(float f) {
    unsigned u = __float_as_uint(f);
    unsigned r = (u + 0x7fffu + ((u >> 16) & 1u)) >> 16;   // RNE
    return (unsigned short)r;
}
__device__ inline float bf2f(unsigned short h) {
    return __uint_as_float(((unsigned)h) << 16);
}

// ---------------- block reduction ----------------
__device__ inline float blk_reduce(float v) {
    __shared__ float sh[BLK];
    int tid = threadIdx.x;
    sh[tid] = v;
    __syncthreads();
    #pragma unroll
    for (int s = BLK / 2; s > 0; s >>= 1) {
        if (tid < s) sh[tid] += sh[tid + s];
        __syncthreads();
    }
    float r = sh[0];
    __syncthreads();
    return r;
}

// ---------------- fp32 normalize + pack (L0, L5) ----------------
__global__ __launch_bounds__(BLK) void wnorm_pack(
    const float* __restrict__ W, float* __restrict__ Wkc,
    float* __restrict__ Wnout, int Mout, int asz)
{
    int o = blockIdx.x;
    const float* w = W + (size_t)o * asz;
    float s = 0.f;
    for (int i = threadIdx.x; i < asz; i += BLK) { float v = w[i]; s = fmaf(v, v, s); }
    float tot = blk_reduce(s);
    float inv = 1.0f / (sqrtf(tot) + 1e-12f);
    for (int i = threadIdx.x; i < asz; i += BLK) {
        float v = w[i] * inv;
        Wkc[(size_t)i * Mout + o] = v;
        if (Wnout) Wnout[(size_t)o * asz + i] = v;
    }
}

// ---------------- bf16 hi/lo normalize + MFMA-fragment pack (L1..L4) ----------------
__global__ __launch_bounds__(BLK) void wnorm_pack_bf16(
    const float* __restrict__ W, short* __restrict__ Cpk, short* __restrict__ Tpk,
    int Cout, int Cin)
{
    int o = blockIdx.x;
    int asz = Cin * 16;
    const float* w = W + (size_t)o * asz;
    float s = 0.f;
    for (int i = threadIdx.x; i < asz; i += BLK) { float v = w[i]; s = fmaf(v, v, s); }
    float tot = blk_reduce(s);
    float inv = 1.0f / (sqrtf(tot) + 1e-12f);
    size_t cTot = (size_t)Cout * asz;
    size_t parStride = (size_t)Cout * 4 * Cin;
    size_t tTot = 4 * parStride;
    for (int i = threadIdx.x; i < asz; i += BLK) {
        float v = w[i] * inv;
        unsigned short hb = f2bf(v);
        unsigned short lb = f2bf(v - bf2f(hb));
        size_t cidx = ((size_t)(i >> 3)) * (Cout * 8) + o * 8 + (i & 7);
        Cpk[cidx] = (short)hb;
        Cpk[cTot + cidx] = (short)lb;
        int c = i >> 4, tap = i & 15, kh = tap >> 2, kw = tap & 3;
        int par = (1 - (kh & 1)) * 2 + (1 - (kw & 1));
        int tt = ((kh >> 1) << 1) | (kw >> 1);
        int q = o * 4 + tt;
        size_t tidx = (size_t)par * parStride + ((size_t)(q >> 3)) * (Cin * 8) + c * 8 + (q & 7);
        Tpk[tidx] = (short)hb;
        Tpk[tTot + tidx] = (short)lb;
    }
}

// ---------------- XCD-aware bijective swizzle ----------------
__device__ inline void xcd_remap(int& bx, int& by, int& bz) {
    int nx = gridDim.x, ny = gridDim.y;
    int nwg = nx * ny * gridDim.z;
    int orig = blockIdx.x + nx * (blockIdx.y + ny * blockIdx.z);
    int q8 = nwg >> 3, r8 = nwg & 7, xcd = orig & 7, sidx = orig >> 3;
    int w = (xcd < r8 ? xcd * (q8 + 1) : r8 * (q8 + 1) + (xcd - r8) * q8) + sidx;
    bx = w % nx; int t = w / nx; by = t % ny; bz = t / ny;
}

// ---------------- bf16x3 MFMA implicit-GEMM forward conv (K=4,S=2,P=1) ----------------
// Double-buffered LDS: one barrier per 32-K step; single-step register prefetch (T14).
__global__ __launch_bounds__(BLK) void conv_gemm_bf16(
    const short* __restrict__ Wpk, const float* __restrict__ x,
    const float* __restrict__ yin, float* __restrict__ out,
    int M, int Cx, int Hx, int Wx, int Hout, int Wout,
    int kchunk, int emode)
{
    __shared__ __align__(16) short Wh[2][4][64][8];
    __shared__ __align__(16) short Wo_[2][4][64][8];
    __shared__ __align__(16) short Xh[2][4][64][8];
    __shared__ __align__(16) short Xo[2][4][64][8];
    int bx, by, bz; xcd_remap(bx, by, bz);
    int tid = threadIdx.x, lane = tid & 63, wid = tid >> 6;
    int HW = Hout * Wout, HWx = Hx * Wx;
    int pbase = bx * 64, m0 = by * 64, kb = bz * kchunk;
    size_t loOff = (size_t)Cx * 16 * M;

    int spl = tid & 63, skb = tid >> 6;
    int sp = pbase + spl;
    int sn = sp / HW; int srr = sp - sn * HW;
    int sho = srr / Wout, swo = srr - sho * Wout;
    const float* xs = x + (size_t)sn * Cx * HWx;
    int h0 = sho * 2 - 1, w0 = swo * 2 - 1;

    int t16 = (skb & 1) * 8;
    int offs[8]; bool valt[8];
    #pragma unroll
    for (int jj = 0; jj < 8; ++jj) {
        int tap = t16 + jj;
        int kh = tap >> 2, kw = tap & 3;
        int h = h0 + kh, w = w0 + kw;
        valt[jj] = ((unsigned)h < (unsigned)Hx) && ((unsigned)w < (unsigned)Wx);
        offs[jj] = h * Wx + w;
    }
    const float* xc = xs + ((size_t)(kb >> 4) + (skb >> 1)) * HWx;

    // prologue: gather k=kb, convert, store into buf 0
    {
        size_t so = ((size_t)((kb >> 3) + skb)) * (M * 8) + (size_t)m0 * 8 + spl * 8;
        float4 w_hi0 = *(const float4*)(Wpk + so);
        float4 w_lo0 = *(const float4*)(Wpk + loOff + so);
        union { short s8[8]; float4 f; } uh, ul;
        #pragma unroll
        for (int jj = 0; jj < 8; ++jj) {
            float gg = valt[jj] ? xc[offs[jj]] : 0.f;
            unsigned short hb = (unsigned short)(__float_as_uint(gg) >> 16);
            uh.s8[jj] = (short)hb;
            ul.s8[jj] = (short)f2bf(gg - bf2f(hb));
        }
        *(float4*)(&Wh[0][skb][spl][0])  = w_hi0;
        *(float4*)(&Wo_[0][skb][spl][0]) = w_lo0;
        *(float4*)(&Xh[0][skb][spl][0])  = uh.f;
        *(float4*)(&Xo[0][skb][spl][0])  = ul.f;
        xc += 2 * HWx;
    }
    __syncthreads();

    f32x4 acc[4] = {};
    int cur = 0;
    for (int k0 = kb; k0 < kb + kchunk; k0 += 32) {
        bool more = (k0 + 32 < kb + kchunk);
        float4 w_hi, w_lo;
        float g[8];
        if (more) {
            size_t so2 = ((size_t)(((k0 + 32) >> 3) + skb)) * (M * 8) + (size_t)m0 * 8 + spl * 8;
            w_hi = *(const float4*)(Wpk + so2);
            w_lo = *(const float4*)(Wpk + loOff + so2);
            #pragma unroll
            for (int jj = 0; jj < 8; ++jj) g[jj] = valt[jj] ? xc[offs[jj]] : 0.f;
            xc += 2 * HWx;
        }
        bf16x8 ah = *(const bf16x8*)(&Wh[cur][lane >> 4][wid * 16 + (lane & 15)][0]);
        bf16x8 al = *(const bf16x8*)(&Wo_[cur][lane >> 4][wid * 16 + (lane & 15)][0]);
        #pragma unroll
        for (int nf = 0; nf < 4; ++nf) {
            bf16x8 bh = *(const bf16x8*)(&Xh[cur][lane >> 4][nf * 16 + (lane & 15)][0]);
            bf16x8 bl = *(const bf16x8*)(&Xo[cur][lane >> 4][nf * 16 + (lane & 15)][0]);
            acc[nf] = __builtin_amdgcn_mfma_f32_16x16x32_bf16(al, bh, acc[nf], 0, 0, 0);
            acc[nf] = __builtin_amdgcn_mfma_f32_16x16x32_bf16(ah, bl, acc[nf], 0, 0, 0);
            acc[nf] = __builtin_amdgcn_mfma_f32_16x16x32_bf16(ah, bh, acc[nf], 0, 0, 0);
        }
        if (more) {
            union { short s8[8]; float4 f; } uh, ul;
            #pragma unroll
            for (int jj = 0; jj < 8; ++jj) {
                float gg = g[jj];
                unsigned short hb = (unsigned short)(__float_as_uint(gg) >> 16);
                uh.s8[jj] = (short)hb;
                ul.s8[jj] = (short)f2bf(gg - bf2f(hb));
            }
            int nxt = cur ^ 1;
            *(float4*)(&Wh[nxt][skb][spl][0])  = w_hi;
            *(float4*)(&Wo_[nxt][skb][spl][0]) = w_lo;
            *(float4*)(&Xh[nxt][skb][spl][0])  = uh.f;
            *(float4*)(&Xo[nxt][skb][spl][0])  = ul.f;
        }
        __syncthreads();
        cur ^= 1;
    }
    int colp = lane & 15, rquad = lane >> 4;
    #pragma unroll
    for (int nf = 0; nf < 4; ++nf) {
        int p = pbase + nf * 16 + colp;
        int n = p / HW; int rr = p - n * HW;
        int ho = rr / Wout, wo = rr - ho * Wout;
        #pragma unroll
        for (int r = 0; r < 4; ++r) {
            int m = m0 + wid * 16 + rquad * 4 + r;
            size_t idx = (((size_t)n * M + m) * Hout + ho) * Wout + wo;
            float v = acc[nf][r];
            if (emode == 0)      out[idx] = fmaxf(MU_F * v - THR_F, 0.f);
            else if (emode == 1) out[idx] = fmaxf(yin[idx] + MU_F * v - THR_F, 0.f);
            else                 atomicAdd(&out[idx], v);
        }
    }
}

// ---------------- bf16x3 MFMA implicit-GEMM transpose conv (double-buffered) ----------------
__global__ __launch_bounds__(BLK) void convt_gemm_bf16(
    const short* __restrict__ Wpk, const float* __restrict__ z,
    const float* __restrict__ aux, float* __restrict__ out,
    int M, int Cz, int Hz, int Wz, int Ho, int Wo, int emode, int SK)
{
    __shared__ __align__(16) short Wh[2][4][64][8];
    __shared__ __align__(16) short Wo_[2][4][64][8];
    __shared__ __align__(16) short Xh[2][4][64][8];
    __shared__ __align__(16) short Xo[2][4][64][8];
    int bx, by, bz; xcd_remap(bx, by, bz);
    int tid = threadIdx.x, lane = tid & 63, wid = tid >> 6;
    int par = bz / SK, chunk = bz - par * SK;
    int hbit = par >> 1, wbit = par & 1;
    int czs = Cz / SK;
    int qb = chunk * czs * 4;
    size_t parS = (size_t)Cz * 4 * M;
    const short* Wp = Wpk + (size_t)par * parS;
    size_t loOff = 4 * parS;
    int Hc = Ho >> 1, Wc = Wo >> 1, HWc = Hc * Wc;
    int pbase = bx * 64, m0 = by * 64;

    int spl = tid & 63, skb = tid >> 6;
    int sp = pbase + spl;
    int sn = sp / HWc; int srr = sp - sn * HWc;
    int shc = srr / Wc, swc = srr - shc * Wc;
    int HWz = Hz * Wz;
    const float* zs = z + (size_t)sn * Cz * HWz;

    int offt[4]; bool valt[4];
    #pragma unroll
    for (int t = 0; t < 4; ++t) {
        int ti = t >> 1, tj = t & 1;
        int hn = shc + hbit - ti, wn = swc + wbit - tj;
        valt[t] = ((unsigned)hn < (unsigned)Hz) && ((unsigned)wn < (unsigned)Wz);
        offt[t] = hn * Wz + wn;
    }
    const float* zc = zs + ((size_t)(qb >> 2) + skb * 2) * HWz;

    // prologue: gather q=qb, convert, store into buf 0
    {
        size_t so = ((size_t)((qb >> 3) + skb)) * (M * 8) + (size_t)m0 * 8 + spl * 8;
        float4 w_hi0 = *(const float4*)(Wp + so);
        float4 w_lo0 = *(const float4*)(Wp + loOff + so);
        union { short s8[8]; float4 f; } uh, ul;
        #pragma unroll
        for (int jj = 0; jj < 8; ++jj) {
            int t = jj & 3;
            float gg = valt[t] ? zc[(jj >> 2) * HWz + offt[t]] : 0.f;
            unsigned short hb = (unsigned short)(__float_as_uint(gg) >> 16);
            uh.s8[jj] = (short)hb;
            ul.s8[jj] = (short)f2bf(gg - bf2f(hb));
        }
        *(float4*)(&Wh[0][skb][spl][0])  = w_hi0;
        *(float4*)(&Wo_[0][skb][spl][0]) = w_lo0;
        *(float4*)(&Xh[0][skb][spl][0])  = uh.f;
        *(float4*)(&Xo[0][skb][spl][0])  = ul.f;
        zc += 8 * HWz;
    }
    __syncthreads();

    f32x4 acc[4] = {};
    int cur = 0;
    for (int q0 = qb; q0 < qb + czs * 4; q0 += 32) {
        bool more = (q0 + 32 < qb + czs * 4);
        float4 w_hi, w_lo;
        float g[8];
        if (more) {
            size_t so2 = ((size_t)(((q0 + 32) >> 3) + skb)) * (M * 8) + (size_t)m0 * 8 + spl * 8;
            w_hi = *(const float4*)(Wp + so2);
            w_lo = *(const float4*)(Wp + loOff + so2);
            #pragma unroll
            for (int jj = 0; jj < 8; ++jj) {
                int t = jj & 3;
                g[jj] = valt[t] ? zc[(jj >> 2) * HWz + offt[t]] : 0.f;
            }
            zc += 8 * HWz;
        }
        bf16x8 ah = *(const bf16x8*)(&Wh[cur][lane >> 4][wid * 16 + (lane & 15)][0]);
        bf16x8 al = *(const bf16x8*)(&Wo_[cur][lane >> 4][wid * 16 + (lane & 15)][0]);
        #pragma unroll
        for (int nf = 0; nf < 4; ++nf) {
            bf16x8 bh = *(const bf16x8*)(&Xh[cur][lane >> 4][nf * 16 + (lane & 15)][0]);
            bf16x8 bl = *(const bf16x8*)(&Xo[cur][lane >> 4][nf * 16 + (lane & 15)][0]);
            acc[nf] = __builtin_amdgcn_mfma_f32_16x16x32_bf16(al, bh, acc[nf], 0, 0, 0);
            acc[nf] = __builtin_amdgcn_mfma_f32_16x16x32_bf16(ah, bl, acc[nf], 0, 0, 0);
            acc[nf] = __builtin_amdgcn_mfma_f32_16x16x32_bf16(ah, bh, acc[nf], 0, 0, 0);
        }
        if (more) {
            union { short s8[8]; float4 f; } uh, ul;
            #pragma unroll
            for (int jj = 0; jj < 8; ++jj) {
                float gg = g[jj];
                unsigned short hb = (unsigned short)(__float_as_uint(gg) >> 16);
                uh.s8[jj] = (short)hb;
                ul.s8[jj] = (short)f2bf(gg - bf2f(hb));
            }
            int nxt = cur ^ 1;
            *(float4*)(&Wh[nxt][skb][spl][0])  = w_hi;
            *(float4*)(&Wo_[nxt][skb][spl][0]) = w_lo;
            *(float4*)(&Xh[nxt][skb][spl][0])  = uh.f;
            *(float4*)(&Xo[nxt][skb][spl][0])  = ul.f;
        }
        __syncthreads();
        cur ^= 1;
    }
    int colp = lane & 15, rquad = lane >> 4;
    #pragma unroll
    for (int nf = 0; nf < 4; ++nf) {
        int p = pbase + nf * 16 + colp;
        int n = p / HWc; int rr = p - n * HWc;
        int hc = rr / Wc, wc = rr - hc * Wc;
        int ho = 2 * hc + hbit, wo = 2 * wc + wbit;
        #pragma unroll
        for (int r = 0; r < 4; ++r) {
            int m = m0 + wid * 16 + rquad * 4 + r;
            size_t idx = (((size_t)n * M + m) * Ho + ho) * Wo + wo;
            float v = acc[nf][r];
            if (emode == 0)      out[idx] = aux[idx] - v;
            else if (emode == 1) out[idx] = v;
            else                 atomicAdd(&out[idx], v);
        }
    }
}

// ---------------- fp32 implicit-GEMM forward conv (L0, L5) ----------------
template <int KK, int Kk, int S, int P>
__global__ __launch_bounds__(BLK) void conv_gemm(
    const float* __restrict__ Wp, const float* __restrict__ x,
    const float* __restrict__ yin, float* __restrict__ out,
    int M, int Ktot, int Cx, int Hx, int Wx, int Hout, int Wout,
    int kchunk, int emode)
{
    __shared__ float Wt[16][64];
    __shared__ float Xt[16][64];
    int tid = threadIdx.x, tx = tid & 15, ty = tid >> 4;
    int HW = Hout * Wout, HWx = Hx * Wx;
    int pbase = blockIdx.x * 64 + tx * 4;
    int n_[4], ho_[4], wo_[4];
    const float* xb_[4];
    #pragma unroll
    for (int j = 0; j < 4; ++j) {
        int p = pbase + j; int n = p / HW; int r = p - n * HW;
        int ho = r / Wout; int wo = r - ho * Wout;
        n_[j] = n; ho_[j] = ho; wo_[j] = wo;
        xb_[j] = x + (size_t)n * Cx * HWx;
    }
    int m0 = blockIdx.y * 64;
    int kb = blockIdx.z * kchunk, ke = kb + kchunk;
    if (ke > Ktot) ke = Ktot;
    float acc[4][4] = {};
    for (int k0 = kb; k0 < ke; k0 += 16) {
        int kr = k0 + ty;
        *(float4*)&Wt[ty][tx * 4] = *(const float4*)&Wp[(size_t)kr * M + m0 + tx * 4];
        int ci = kr / KK; int t = kr - ci * KK; int kh = t / Kk; int kw = t - kh * Kk;
        int cio = ci * HWx;
        float g[4];
        #pragma unroll
        for (int j = 0; j < 4; ++j) {
            int h = ho_[j] * S - P + kh, w = wo_[j] * S - P + kw;
            g[j] = ((unsigned)h < (unsigned)Hx && (unsigned)w < (unsigned)Wx)
                 ? xb_[j][cio + h * Wx + w] : 0.f;
        }
        *(float4*)&Xt[ty][tx * 4] = make_float4(g[0], g[1], g[2], g[3]);
        __syncthreads();
        #pragma unroll
        for (int kk = 0; kk < 16; ++kk) {
            float4 a = *(float4*)&Wt[kk][ty * 4];
            float4 b = *(float4*)&Xt[kk][tx * 4];
            float aa[4] = {a.x, a.y, a.z, a.w};
            float bb[4] = {b.x, b.y, b.z, b.w};
            #pragma unroll
            for (int i = 0; i < 4; ++i)
                #pragma unroll
                for (int j = 0; j < 4; ++j)
                    acc[i][j] = fmaf(aa[i], bb[j], acc[i][j]);
        }
        __syncthreads();
    }
    #pragma unroll
    for (int i = 0; i < 4; ++i) {
        int m = m0 + ty * 4 + i;
        #pragma unroll
        for (int j = 0; j < 4; ++j) {
            size_t idx = (((size_t)n_[j] * M + m) * Hout + ho_[j]) * Wout + wo_[j];
            float v = acc[i][j];
            if (emode == 0)      out[idx] = fmaxf(MU_F * v - THR_F, 0.f);
            else if (emode == 1) out[idx] = fmaxf(yin[idx] + MU_F * v - THR_F, 0.f);
            else                 atomicAdd(&out[idx], v);
        }
    }
}

// ---------------- 1x1-source transpose conv as plain GEMM (L5) ----------------
__global__ __launch_bounds__(BLK) void outer_gemm(
    const float* __restrict__ Wp, const float* __restrict__ zin,
    const float* __restrict__ aux, float* __restrict__ out,
    int M, int Kz, int emode)
{
    __shared__ float Wt[16][64];
    __shared__ float Xt[16][64];
    int tid = threadIdx.x, tx = tid & 15, ty = tid >> 4;
    int m0 = blockIdx.y * 64;
    float acc[4][4] = {};
    for (int k0 = 0; k0 < Kz; k0 += 16) {
        int kr = k0 + ty;
        *(float4*)&Wt[ty][tx * 4] = *(const float4*)&Wp[(size_t)kr * M + m0 + tx * 4];
        float g[4];
        #pragma unroll
        for (int j = 0; j < 4; ++j) g[j] = zin[(size_t)(tx * 4 + j) * Kz + kr];
        *(float4*)&Xt[ty][tx * 4] = make_float4(g[0], g[1], g[2], g[3]);
        __syncthreads();
        #pragma unroll
        for (int kk = 0; kk < 16; ++kk) {
            float4 a = *(float4*)&Wt[kk][ty * 4];
            float4 b = *(float4*)&Xt[kk][tx * 4];
            float aa[4] = {a.x, a.y, a.z, a.w};
            float bb[4] = {b.x, b.y, b.z, b.w};
            #pragma unroll
            for (int i = 0; i < 4; ++i)
                #pragma unroll
                for (int j = 0; j < 4; ++j)
                    acc[i][j] = fmaf(aa[i], bb[j], acc[i][j]);
        }
        __syncthreads();
    }
    #pragma unroll
    for (int i = 0; i < 4; ++i) {
        int m = m0 + ty * 4 + i;
        #pragma unroll
        for (int j = 0; j < 4; ++j) {
            int n = tx * 4 + j;
            size_t idx = (size_t)n * M + m;
            float v = acc[i][j];
            out[idx] = (emode == 0) ? (aux[idx] - v) : v;
        }
    }
}

// ---------------- M=3 transpose conv (image space, fp32) ----------------
__global__ __launch_bounds__(BLK) void convt_m3(
    const float* __restrict__ Wkc0, const float* __restrict__ z,
    const float* __restrict__ aux, float* __restrict__ out,
    int Cz, int Hz, int Wz, int Ho, int Wo, int emode)
{
    __shared__ float Wl[64 * 4 * 3];
    int tid = threadIdx.x;
    int hbit = blockIdx.z >> 1, wbit = blockIdx.z & 1;
    int khp = 1 - hbit, kwp = 1 - wbit;
    int Ktot = Cz * 4;
    for (int kidx = tid; kidx < Ktot; kidx += BLK) {
        int cz = kidx >> 2, t = kidx & 3, ti = t >> 1, tj = t & 1;
        int tap = (khp + 2 * ti) * 4 + (kwp + 2 * tj);
        Wl[kidx * 3 + 0] = Wkc0[(0 * 16 + tap) * 64 + cz];
        Wl[kidx * 3 + 1] = Wkc0[(1 * 16 + tap) * 64 + cz];
        Wl[kidx * 3 + 2] = Wkc0[(2 * 16 + tap) * 64 + cz];
    }
    __syncthreads();
    int Hc = Ho >> 1, Wc = Wo >> 1, HWc = Hc * Wc;
    int p = blockIdx.x * BLK + tid;
    int n = p / HWc, r = p - n * HWc, hc = r / Wc, wc = r - (r / Wc) * Wc;
    const float* zb = z + (size_t)n * Cz * Hz * Wz;
    int offs[4]; bool val[4];
    #pragma unroll
    for (int t = 0; t < 4; ++t) {
        int ti = t >> 1, tj = t & 1;
        int hn = hc + hbit - ti, wn = wc + wbit - tj;
        val[t] = ((unsigned)hn < (unsigned)Hz) && ((unsigned)wn < (unsigned)Wz);
        offs[t] = hn * Wz + wn;
    }
    float a0 = 0.f, a1 = 0.f, a2 = 0.f;
    int HWz = Hz * Wz;
    for (int cz = 0; cz < Cz; ++cz) {
        const float* base = zb + cz * HWz;
        #pragma unroll
        for (int t = 0; t < 4; ++t) {
            float g = val[t] ? base[offs[t]] : 0.f;
            int wi = (cz * 4 + t) * 3;
            a0 = fmaf(g, Wl[wi + 0], a0);
            a1 = fmaf(g, Wl[wi + 1], a1);
            a2 = fmaf(g, Wl[wi + 2], a2);
        }
    }
    int ho = 2 * hc + hbit, wo = 2 * wc + wbit;
    #pragma unroll
    for (int u = 0; u < 3; ++u) {
        float v = (u == 0) ? a0 : (u == 1) ? a1 : a2;
        size_t idx = (((size_t)n * 3 + u) * Ho + ho) * Wo + wo;
        out[idx] = (emode == 0) ? (aux[idx] - v) : tanhf(v);
    }
}

// ---------------- vectorized epilogues / elementwise (n % 4 == 0) ----------------
__global__ __launch_bounds__(BLK) void shrink_epi_v4(
    const float* __restrict__ p, const float* __restrict__ y,
    float* __restrict__ o, int n4, int mode)
{
    int i = blockIdx.x * BLK + threadIdx.x;
    if (i >= n4) return;
    float4 pv = ((const float4*)p)[i];
    float4 r;
    if (mode == 1) {
        float4 yv = ((const float4*)y)[i];
        r.x = fmaxf(yv.x + MU_F * pv.x - THR_F, 0.f);
        r.y = fmaxf(yv.y + MU_F * pv.y - THR_F, 0.f);
        r.z = fmaxf(yv.z + MU_F * pv.z - THR_F, 0.f);
        r.w = fmaxf(yv.w + MU_F * pv.w - THR_F, 0.f);
    } else {
        r.x = fmaxf(MU_F * pv.x - THR_F, 0.f);
        r.y = fmaxf(MU_F * pv.y - THR_F, 0.f);
        r.z = fmaxf(MU_F * pv.z - THR_F, 0.f);
        r.w = fmaxf(MU_F * pv.w - THR_F, 0.f);
    }
    ((float4*)o)[i] = r;
}

__global__ __launch_bounds__(BLK) void res_epi_v4(
    const float* __restrict__ aux, const float* __restrict__ acc,
    float* __restrict__ o, int n4)
{
    int i = blockIdx.x * BLK + threadIdx.x;
    if (i >= n4) return;
    float4 a = ((const float4*)aux)[i];
    float4 b = ((const float4*)acc)[i];
    ((float4*)o)[i] = make_float4(a.x - b.x, a.y - b.y, a.z - b.z, a.w - b.w);
}

__global__ __launch_bounds__(BLK) void y_update_v4(
    const float* __restrict__ z, const float* __restrict__ zo,
    float* __restrict__ y, int n4, float c)
{
    int i = blockIdx.x * BLK + threadIdx.x;
    if (i >= n4) return;
    float4 zv = ((const float4*)z)[i];
    float4 ov = ((const float4*)zo)[i];
    ((float4*)y)[i] = make_float4(
        fmaf(c, zv.x - ov.x, zv.x), fmaf(c, zv.y - ov.y, zv.y),
        fmaf(c, zv.z - ov.z, zv.z), fmaf(c, zv.w - ov.w, zv.w));
}

// ---------------- two-stage BN stats ----------------
__global__ __launch_bounds__(BLK) void bn_stats_part(
    const float* __restrict__ x, float* __restrict__ stats,
    int N, int C, int HW, int nblk)
{
    int c = blockIdx.x, b = blockIdx.y;
    int cnt = N * HW;
    float s = 0.f, s2 = 0.f;
    for (int i = b * BLK + threadIdx.x; i < cnt; i += nblk * BLK) {
        int n = i / HW, hw = i - n * HW;
        float v = x[((size_t)n * C + c) * HW + hw];
        s += v; s2 = fmaf(v, v, s2);
    }
    float ts  = blk_reduce(s);
    float ts2 = blk_reduce(s2);
    if (threadIdx.x == 0) {
        atomicAdd(&stats[c], ts);
        atomicAdd(&stats[C + c], ts2);
    }
}
__global__ __launch_bounds__(BLK) void bn_finalize(
    const float* __restrict__ stats, float* __restrict__ mean,
    float* __restrict__ rstd, int C, int cnt)
{
    int c = blockIdx.x * BLK + threadIdx.x;
    if (c >= C) return;
    float m = stats[c] / cnt;
    float var = stats[C + c] / cnt - m * m;
    mean[c] = m;
    rstd[c] = rsqrtf(var + 1e-5f);
}

// ---------------- BN apply + activation, vectorized ----------------
__global__ __launch_bounds__(BLK) void bn_act_v4(
    const float* __restrict__ x, const float* __restrict__ mean,
    const float* __restrict__ rstd, float* __restrict__ out,
    int n4, int C, int HW, int use_bn, int act)
{
    int i = blockIdx.x * BLK + threadIdx.x;
    if (i >= n4) return;
    float4 v = ((const float4*)x)[i];
    float e[4] = {v.x, v.y, v.z, v.w};
    int base = i * 4;
    #pragma unroll
    for (int j = 0; j < 4; ++j) {
        float t = e[j];
        if (use_bn) { int c = ((base + j) / HW) % C; t = (t - mean[c]) * rstd[c]; }
        e[j] = (act == 0) ? ((t >= 0.f) ? t : 0.2f * t) : fmaxf(t, 0.f);
    }
    ((float4*)out)[i] = make_float4(e[0], e[1], e[2], e[3]);
}

// ---------------- per-row L2 normalize ----------------
__global__ __launch_bounds__(128) void rownorm_kernel(
    const float* __restrict__ z, float* __restrict__ out, float* __restrict__ zvec)
{
    __shared__ float sh[128];
    int r = blockIdx.x, tid = threadIdx.x;
    float v = z[r * 128 + tid];
    sh[tid] = v * v;
    __syncthreads();
    #pragma unroll
    for (int s = 64; s > 0; s >>= 1) {
        if (tid < s) sh[tid] += sh[tid + s];
        __syncthreads();
    }
    float nrm = fmaxf(sqrtf(sh[0]), 1e-12f);
    float o = v / nrm;
    out[r * 128 + tid] = o;
    zvec[r * 128 + tid] = o;
}

static inline int gdiv(int a, int b) { return (a + b - 1) / b; }

extern "C" void kernel_launch(void* const* d_in, const int* in_sizes, int n_in,
                              void* d_out, int out_size, void* d_ws, size_t ws_size,
                              hipStream_t stream)
{
    const float* x = (const float*)d_in[0];
    const float* W[6];
    for (int i = 0; i < 6; ++i) W[i] = (const float*)d_in[1 + i];
    float* ws  = (float*)d_ws;
    float* out = (float*)d_out;

    const int Cin[6]  = {3, 64, 128, 256, 512, 1024};
    const int Cout[6] = {64, 128, 256, 512, 1024, 128};
    const int Hin[6]  = {96, 48, 24, 12, 6, 3};
    const int Hout[6] = {48, 24, 12, 6, 3, 1};
    const int N = 64;
    const int SKc[6] = {1, 1, 2, 4, 8, 1};
    const int SKt[6] = {1, 1, 1, 2, 4, 1};

    // ---- workspace layout: ~66.53M floats = 253.8 MB ----
    size_t off = 0;
    float* Wkc0 = ws + off; off += 3072;
    float* Wkc5 = ws + off; off += 1179648;
    float* Wn5  = ws + off; off += 1179648;
    const size_t csz[5] = {0, 131072, 524288, 2097152, 8388608};
    short* Cpk[5]; short* Tpk[5];
    {
        short* sbase = (short*)(ws + off);
        size_t soff = 0;
        for (int L = 1; L < 5; ++L) { Cpk[L] = sbase + soff; soff += 2 * csz[L]; }
        for (int L = 1; L < 5; ++L) { Tpk[L] = sbase + soff; soff += 2 * csz[L]; }
        off += soff / 2;
    }
    const size_t POOL = 30081024;
    float* pool = ws + off; off += POOL;
    float* xb   = ws + off; off += 9437184;
    float* mean = ws + off; off += 1024;
    float* rstd = ws + off; off += 1024;
    float* stats= ws + off; off += 2048;
    float* zvec = ws + off; off += 8192;
    float* pbuf = ws + off; off += 2359296;

    // ---- normalize + pack dictionaries ----
    wnorm_pack<<<64, BLK, 0, stream>>>(W[0], Wkc0, nullptr, 64, 48);
    for (int L = 1; L < 5; ++L)
        wnorm_pack_bf16<<<Cout[L], BLK, 0, stream>>>(W[L], Cpk[L], Tpk[L], Cout[L], Cin[L]);
    wnorm_pack<<<128, BLK, 0, stream>>>(W[5], Wkc5, Wn5, 128, 9216);

    // ---- FISTA momentum coefficients ----
    double td = 1.0; float cc[3];
    for (int i = 0; i < 3; ++i) {
        double tn = (1.0 + sqrt(1.0 + 4.0 * td * td)) * 0.5;
        cc[i] = (float)((td - 1.0) / tn);
        td = tn;
    }

    auto run_bn_stats = [&](const float* src, int C, int HW) {
        int cnt = N * HW;
        int nblk = 2048 / C; if (nblk < 1) nblk = 1;
        int maxb = gdiv(cnt, BLK); if (nblk > maxb) nblk = maxb;
        hipMemsetAsync(stats, 0, 2 * C * sizeof(float), stream);
        bn_stats_part<<<dim3(C, nblk), BLK, 0, stream>>>(src, stats, N, C, HW, nblk);
        bn_finalize<<<gdiv(C, BLK), BLK, 0, stream>>>(stats, mean, rstd, C, cnt);
    };

    const float* in = x;
    for (int L = 0; L < 6; ++L) {
        int zTot = N * Cout[L] * Hout[L] * Hout[L];
        int xTot = N * Cin[L] * Hin[L] * Hin[L];
        int npix = N * Hout[L] * Hout[L];
        dim3 ge4(gdiv(zTot / 4, BLK));
        dim3 gr4(gdiv(xTot / 4, BLK));

        float* zA = pool;
        float* zB = pool + (size_t)zTot;
        float* yb = pool + (size_t)2 * zTot;
        float* rb = pool + (size_t)3 * zTot;

        auto launch_conv = [&](const float* src, const float* y, float* dst, int mode) {
            if (L == 5) {
                hipMemsetAsync(pbuf, 0, (size_t)zTot * 4, stream);
                conv_gemm<9, 3, 1, 0><<<dim3(1, 2, 72), BLK, 0, stream>>>(Wkc5, src,
                    nullptr, pbuf, 128, 9216, 1024, 3, 3, 1, 1, 128, 2);
                shrink_epi_v4<<<gdiv(zTot / 4, BLK), BLK, 0, stream>>>(pbuf, y, dst, zTot / 4, mode);
            } else if (L == 0) {
                conv_gemm<16, 4, 2, 1><<<dim3(npix / 64, 1), BLK, 0, stream>>>(
                    Wkc0, src, y, dst, 64, 48, 3, 96, 96, 48, 48, 48, mode);
            } else if (SKc[L] == 1) {
                conv_gemm_bf16<<<dim3(npix / 64, Cout[L] / 64), BLK, 0, stream>>>(
                    Cpk[L], src, y, dst, Cout[L], Cin[L], Hin[L], Hin[L],
                    Hout[L], Hout[L], Cin[L] * 16, mode);
            } else {
                int sk = SKc[L];
                hipMemsetAsync(pbuf, 0, (size_t)zTot * 4, stream);
                conv_gemm_bf16<<<dim3(npix / 64, Cout[L] / 64, sk), BLK, 0, stream>>>(
                    Cpk[L], src, nullptr, pbuf, Cout[L], Cin[L], Hin[L], Hin[L],
                    Hout[L], Hout[L], Cin[L] * 16 / sk, 2);
                shrink_epi_v4<<<gdiv(zTot / 4, BLK), BLK, 0, stream>>>(pbuf, y, dst, zTot / 4, mode);
            }
        };

        // z0 = shrink(MU * conv(in))
        launch_conv(in, nullptr, zA, 0);

        float* z = zA; float* zo = zB;
        for (int it = 0; it < 3; ++it) {
            const float* ybp;
            if (it == 0) {
                ybp = z;                 // c = 0 -> y == z
            } else {
                y_update_v4<<<ge4, BLK, 0, stream>>>(z, zo, yb, zTot / 4, cc[it]);
                ybp = yb;
            }
            // r = in - convT(y)
            if (L == 0) {
                convt_m3<<<dim3(N * 48 * 48 / BLK, 1, 4), BLK, 0, stream>>>(
                    Wkc0, ybp, in, rb, 64, 48, 48, 96, 96, 0);
            } else if (L < 5) {
                int xpixc = N * (Hin[L] / 2) * (Hin[L] / 2);
                int sk = SKt[L];
                if (sk == 1) {
                    convt_gemm_bf16<<<dim3(xpixc / 64, Cin[L] / 64, 4), BLK, 0, stream>>>(
                        Tpk[L], ybp, in, rb, Cin[L], Cout[L], Hout[L], Hout[L],
                        Hin[L], Hin[L], 0, 1);
                } else {
                    hipMemsetAsync(rb, 0, (size_t)xTot * 4, stream);
                    convt_gemm_bf16<<<dim3(xpixc / 64, Cin[L] / 64, 4 * sk), BLK, 0, stream>>>(
                        Tpk[L], ybp, nullptr, rb, Cin[L], Cout[L], Hout[L], Hout[L],
                        Hin[L], Hin[L], 2, sk);
                    res_epi_v4<<<gr4, BLK, 0, stream>>>(in, rb, rb, xTot / 4);
                }
            } else {
                outer_gemm<<<dim3(1, 144), BLK, 0, stream>>>(Wn5, ybp, in, rb, 9216, 128, 0);
            }
            // z_new = shrink(y + MU*conv(r))
            launch_conv(rb, ybp, zo, 1);
            float* tmp = z; z = zo; zo = tmp;
        }

        int HW = Hout[L] * Hout[L];
        if (L == 0) {
            bn_act_v4<<<ge4, BLK, 0, stream>>>(z, nullptr, nullptr, xb, zTot / 4, Cout[L], HW, 0, 0);
            in = xb;
        } else if (L < 5) {
            run_bn_stats(z, Cout[L], HW);
            bn_act_v4<<<ge4, BLK, 0, stream>>>(z, mean, rstd, xb, zTot / 4, Cout[L], HW, 1, 0);
            in = xb;
        } else {
            rownorm_kernel<<<64, 128, 0, stream>>>(z, out, zvec);
        }
    }

    // ---- decoder (bf16x3 convT stages, fp32 elsewhere) ----
    float* zA = pool;
    float* zB = pool + 9437184;
    {
        int oT = N * 1024 * 9;
        outer_gemm<<<dim3(1, 144), BLK, 0, stream>>>(Wn5, zvec, nullptr, zA, 9216, 128, 1);
        run_bn_stats(zA, 1024, 9);
        bn_act_v4<<<gdiv(oT / 4, BLK), BLK, 0, stream>>>(zA, mean, rstd, zB, oT / 4, 1024, 9, 1, 1);
    }
    float* cur = zB;
    for (int i = 4; i >= 1; --i) {
        int oT = N * Cin[i] * Hin[i] * Hin[i];
        int xpixc = N * (Hin[i] / 2) * (Hin[i] / 2);
        int sk = SKt[i];
        if (sk == 1) {
            convt_gemm_bf16<<<dim3(xpixc / 64, Cin[i] / 64, 4), BLK, 0, stream>>>(
                Tpk[i], cur, nullptr, zA, Cin[i], Cout[i], Hout[i], Hout[i],
                Hin[i], Hin[i], 1, 1);
        } else {
            hipMemsetAsync(zA, 0, (size_t)oT * 4, stream);
            convt_gemm_bf16<<<dim3(xpixc / 64, Cin[i] / 64, 4 * sk), BLK, 0, stream>>>(
                Tpk[i], cur, nullptr, zA, Cin[i], Cout[i], Hout[i], Hout[i],
                Hin[i], Hin[i], 2, sk);
        }
        run_bn_stats(zA, Cin[i], Hin[i] * Hin[i]);
        bn_act_v4<<<gdiv(oT / 4, BLK), BLK, 0, stream>>>(zA, mean, rstd, zB, oT / 4,
            Cin[i], Hin[i] * Hin[i], 1, 1);
        cur = zB;
    }
    convt_m3<<<dim3(N * 48 * 48 / BLK, 1, 4), BLK, 0, stream>>>(
        Wkc0, cur, nullptr, out + 8192, 64, 48, 48, 96, 96, 2);
}

// Round 14
// 3580.286 us; speedup vs baseline: 1.5556x; 1.0619x over previous
//
#include <hip/hip_runtime.h>
#include <math.h>

#define BLK 256
static constexpr float MU_F  = 0.1f;
static constexpr float THR_F = 0.01f;

typedef __attribute__((ext_vector_type(8))) short bf16x8;
typedef __attribute__((ext_vector_type(4))) float f32x4;

__device__ inline unsigned short f2bf(float f) {
    unsigned u = __float_as_uint(f);
    unsigned r = (u + 0x7fffu + ((u >> 16) & 1u)) >> 16;   // RNE
    return (unsigned short)r;
}
__device__ inline float bf2f(unsigned short h) {
    return __uint_as_float(((unsigned)h) << 16);
}

// ---------------- block reduction ----------------
__device__ inline float blk_reduce(float v) {
    __shared__ float sh[BLK];
    int tid = threadIdx.x;
    sh[tid] = v;
    __syncthreads();
    #pragma unroll
    for (int s = BLK / 2; s > 0; s >>= 1) {
        if (tid < s) sh[tid] += sh[tid + s];
        __syncthreads();
    }
    float r = sh[0];
    __syncthreads();
    return r;
}

// ---------------- fp32 normalize + pack (L0, L5) ----------------
__global__ __launch_bounds__(BLK) void wnorm_pack(
    const float* __restrict__ W, float* __restrict__ Wkc,
    float* __restrict__ Wnout, int Mout, int asz)
{
    int o = blockIdx.x;
    const float* w = W + (size_t)o * asz;
    float s = 0.f;
    for (int i = threadIdx.x; i < asz; i += BLK) { float v = w[i]; s = fmaf(v, v, s); }
    float tot = blk_reduce(s);
    float inv = 1.0f / (sqrtf(tot) + 1e-12f);
    for (int i = threadIdx.x; i < asz; i += BLK) {
        float v = w[i] * inv;
        Wkc[(size_t)i * Mout + o] = v;
        if (Wnout) Wnout[(size_t)o * asz + i] = v;
    }
}

// ---------------- bf16 hi/lo normalize + MFMA-fragment pack (L1..L4) ----------------
__global__ __launch_bounds__(BLK) void wnorm_pack_bf16(
    const float* __restrict__ W, short* __restrict__ Cpk, short* __restrict__ Tpk,
    int Cout, int Cin)
{
    int o = blockIdx.x;
    int asz = Cin * 16;
    const float* w = W + (size_t)o * asz;
    float s = 0.f;
    for (int i = threadIdx.x; i < asz; i += BLK) { float v = w[i]; s = fmaf(v, v, s); }
    float tot = blk_reduce(s);
    float inv = 1.0f / (sqrtf(tot) + 1e-12f);
    size_t cTot = (size_t)Cout * asz;
    size_t parStride = (size_t)Cout * 4 * Cin;
    size_t tTot = 4 * parStride;
    for (int i = threadIdx.x; i < asz; i += BLK) {
        float v = w[i] * inv;
        unsigned short hb = f2bf(v);
        unsigned short lb = f2bf(v - bf2f(hb));
        size_t cidx = ((size_t)(i >> 3)) * (Cout * 8) + o * 8 + (i & 7);
        Cpk[cidx] = (short)hb;
        Cpk[cTot + cidx] = (short)lb;
        int c = i >> 4, tap = i & 15, kh = tap >> 2, kw = tap & 3;
        int par = (1 - (kh & 1)) * 2 + (1 - (kw & 1));
        int tt = ((kh >> 1) << 1) | (kw >> 1);
        int q = o * 4 + tt;
        size_t tidx = (size_t)par * parStride + ((size_t)(q >> 3)) * (Cin * 8) + c * 8 + (q & 7);
        Tpk[tidx] = (short)hb;
        Tpk[tTot + tidx] = (short)lb;
    }
}

// ---------------- XCD-aware bijective swizzle ----------------
__device__ inline void xcd_remap(int& bx, int& by, int& bz) {
    int nx = gridDim.x, ny = gridDim.y;
    int nwg = nx * ny * gridDim.z;
    int orig = blockIdx.x + nx * (blockIdx.y + ny * blockIdx.z);
    int q8 = nwg >> 3, r8 = nwg & 7, xcd = orig & 7, sidx = orig >> 3;
    int w = (xcd < r8 ? xcd * (q8 + 1) : r8 * (q8 + 1) + (xcd - r8) * q8) + sidx;
    bx = w % nx; int t = w / nx; by = t % ny; bz = t / ny;
}

// ---------------- bf16x3 MFMA implicit-GEMM forward conv (K=4,S=2,P=1) ----------------
// Software-pipelined: next step's gathers issued before MFMA cluster (T14).
__global__ __launch_bounds__(BLK) void conv_gemm_bf16(
    const short* __restrict__ Wpk, const float* __restrict__ x,
    const float* __restrict__ yin, float* __restrict__ out,
    int M, int Cx, int Hx, int Wx, int Hout, int Wout,
    int kchunk, int emode)
{
    __shared__ __align__(16) short Wh[4][64][8];
    __shared__ __align__(16) short Wo_[4][64][8];
    __shared__ __align__(16) short Xh[4][64][8];
    __shared__ __align__(16) short Xo[4][64][8];
    int bx, by, bz; xcd_remap(bx, by, bz);
    int tid = threadIdx.x, lane = tid & 63, wid = tid >> 6;
    int HW = Hout * Wout, HWx = Hx * Wx;
    int pbase = bx * 64, m0 = by * 64, kb = bz * kchunk;
    size_t loOff = (size_t)Cx * 16 * M;

    int spl = tid & 63, skb = tid >> 6;
    int sp = pbase + spl;
    int sn = sp / HW; int srr = sp - sn * HW;
    int sho = srr / Wout, swo = srr - sho * Wout;
    const float* xs = x + (size_t)sn * Cx * HWx;
    int h0 = sho * 2 - 1, w0 = swo * 2 - 1;

    int t16 = (skb & 1) * 8;
    int offs[8]; bool valt[8];
    #pragma unroll
    for (int jj = 0; jj < 8; ++jj) {
        int tap = t16 + jj;
        int kh = tap >> 2, kw = tap & 3;
        int h = h0 + kh, w = w0 + kw;
        valt[jj] = ((unsigned)h < (unsigned)Hx) && ((unsigned)w < (unsigned)Wx);
        offs[jj] = h * Wx + w;
    }
    const float* xc = xs + ((size_t)(kb >> 4) + (skb >> 1)) * HWx;

    // prologue gather (k = kb)
    size_t so = ((size_t)((kb >> 3) + skb)) * (M * 8) + (size_t)m0 * 8 + spl * 8;
    float4 w_hi = *(const float4*)(Wpk + so);
    float4 w_lo = *(const float4*)(Wpk + loOff + so);
    float g[8];
    #pragma unroll
    for (int jj = 0; jj < 8; ++jj) g[jj] = valt[jj] ? xc[offs[jj]] : 0.f;
    xc += 2 * HWx;

    f32x4 acc[4] = {};
    for (int k0 = kb; k0 < kb + kchunk; k0 += 32) {
        // convert + store current step into LDS
        *(float4*)(&Wh[skb][spl][0])  = w_hi;
        *(float4*)(&Wo_[skb][spl][0]) = w_lo;
        {
            union { short s8[8]; float4 f; } uh, ul;
            #pragma unroll
            for (int jj = 0; jj < 8; ++jj) {
                float gg = g[jj];
                unsigned short hb = (unsigned short)(__float_as_uint(gg) >> 16);
                uh.s8[jj] = (short)hb;
                ul.s8[jj] = (short)f2bf(gg - bf2f(hb));
            }
            *(float4*)(&Xh[skb][spl][0]) = uh.f;
            *(float4*)(&Xo[skb][spl][0]) = ul.f;
        }
        __syncthreads();
        // prefetch next step (loads overlap MFMA + barrier)
        if (k0 + 32 < kb + kchunk) {
            size_t so2 = ((size_t)(((k0 + 32) >> 3) + skb)) * (M * 8) + (size_t)m0 * 8 + spl * 8;
            w_hi = *(const float4*)(Wpk + so2);
            w_lo = *(const float4*)(Wpk + loOff + so2);
            #pragma unroll
            for (int jj = 0; jj < 8; ++jj) g[jj] = valt[jj] ? xc[offs[jj]] : 0.f;
            xc += 2 * HWx;
        }
        bf16x8 ah = *(const bf16x8*)(&Wh[lane >> 4][wid * 16 + (lane & 15)][0]);
        bf16x8 al = *(const bf16x8*)(&Wo_[lane >> 4][wid * 16 + (lane & 15)][0]);
        #pragma unroll
        for (int nf = 0; nf < 4; ++nf) {
            bf16x8 bh = *(const bf16x8*)(&Xh[lane >> 4][nf * 16 + (lane & 15)][0]);
            bf16x8 bl = *(const bf16x8*)(&Xo[lane >> 4][nf * 16 + (lane & 15)][0]);
            acc[nf] = __builtin_amdgcn_mfma_f32_16x16x32_bf16(al, bh, acc[nf], 0, 0, 0);
            acc[nf] = __builtin_amdgcn_mfma_f32_16x16x32_bf16(ah, bl, acc[nf], 0, 0, 0);
            acc[nf] = __builtin_amdgcn_mfma_f32_16x16x32_bf16(ah, bh, acc[nf], 0, 0, 0);
        }
        __syncthreads();
    }
    int colp = lane & 15, rquad = lane >> 4;
    #pragma unroll
    for (int nf = 0; nf < 4; ++nf) {
        int p = pbase + nf * 16 + colp;
        int n = p / HW; int rr = p - n * HW;
        int ho = rr / Wout, wo = rr - ho * Wout;
        #pragma unroll
        for (int r = 0; r < 4; ++r) {
            int m = m0 + wid * 16 + rquad * 4 + r;
            size_t idx = (((size_t)n * M + m) * Hout + ho) * Wout + wo;
            float v = acc[nf][r];
            if (emode == 0)      out[idx] = fmaxf(MU_F * v - THR_F, 0.f);
            else if (emode == 1) out[idx] = fmaxf(yin[idx] + MU_F * v - THR_F, 0.f);
            else                 atomicAdd(&out[idx], v);
        }
    }
}

// ---------------- bf16x3 MFMA implicit-GEMM transpose conv (pipelined) ----------------
__global__ __launch_bounds__(BLK) void convt_gemm_bf16(
    const short* __restrict__ Wpk, const float* __restrict__ z,
    const float* __restrict__ aux, float* __restrict__ out,
    int M, int Cz, int Hz, int Wz, int Ho, int Wo, int emode, int SK)
{
    __shared__ __align__(16) short Wh[4][64][8];
    __shared__ __align__(16) short Wo_[4][64][8];
    __shared__ __align__(16) short Xh[4][64][8];
    __shared__ __align__(16) short Xo[4][64][8];
    int bx, by, bz; xcd_remap(bx, by, bz);
    int tid = threadIdx.x, lane = tid & 63, wid = tid >> 6;
    int par = bz / SK, chunk = bz - par * SK;
    int hbit = par >> 1, wbit = par & 1;
    int czs = Cz / SK;
    int qb = chunk * czs * 4;
    size_t parS = (size_t)Cz * 4 * M;
    const short* Wp = Wpk + (size_t)par * parS;
    size_t loOff = 4 * parS;
    int Hc = Ho >> 1, Wc = Wo >> 1, HWc = Hc * Wc;
    int pbase = bx * 64, m0 = by * 64;

    int spl = tid & 63, skb = tid >> 6;
    int sp = pbase + spl;
    int sn = sp / HWc; int srr = sp - sn * HWc;
    int shc = srr / Wc, swc = srr - shc * Wc;
    int HWz = Hz * Wz;
    const float* zs = z + (size_t)sn * Cz * HWz;

    int offt[4]; bool valt[4];
    #pragma unroll
    for (int t = 0; t < 4; ++t) {
        int ti = t >> 1, tj = t & 1;
        int hn = shc + hbit - ti, wn = swc + wbit - tj;
        valt[t] = ((unsigned)hn < (unsigned)Hz) && ((unsigned)wn < (unsigned)Wz);
        offt[t] = hn * Wz + wn;
    }
    const float* zc = zs + ((size_t)(qb >> 2) + skb * 2) * HWz;

    // prologue gather (q = qb)
    size_t so = ((size_t)((qb >> 3) + skb)) * (M * 8) + (size_t)m0 * 8 + spl * 8;
    float4 w_hi = *(const float4*)(Wp + so);
    float4 w_lo = *(const float4*)(Wp + loOff + so);
    float g[8];
    #pragma unroll
    for (int jj = 0; jj < 8; ++jj) {
        int t = jj & 3;
        g[jj] = valt[t] ? zc[(jj >> 2) * HWz + offt[t]] : 0.f;
    }
    zc += 8 * HWz;

    f32x4 acc[4] = {};
    for (int q0 = qb; q0 < qb + czs * 4; q0 += 32) {
        *(float4*)(&Wh[skb][spl][0])  = w_hi;
        *(float4*)(&Wo_[skb][spl][0]) = w_lo;
        {
            union { short s8[8]; float4 f; } uh, ul;
            #pragma unroll
            for (int jj = 0; jj < 8; ++jj) {
                float gg = g[jj];
                unsigned short hb = (unsigned short)(__float_as_uint(gg) >> 16);
                uh.s8[jj] = (short)hb;
                ul.s8[jj] = (short)f2bf(gg - bf2f(hb));
            }
            *(float4*)(&Xh[skb][spl][0]) = uh.f;
            *(float4*)(&Xo[skb][spl][0]) = ul.f;
        }
        __syncthreads();
        if (q0 + 32 < qb + czs * 4) {
            size_t so2 = ((size_t)(((q0 + 32) >> 3) + skb)) * (M * 8) + (size_t)m0 * 8 + spl * 8;
            w_hi = *(const float4*)(Wp + so2);
            w_lo = *(const float4*)(Wp + loOff + so2);
            #pragma unroll
            for (int jj = 0; jj < 8; ++jj) {
                int t = jj & 3;
                g[jj] = valt[t] ? zc[(jj >> 2) * HWz + offt[t]] : 0.f;
            }
            zc += 8 * HWz;
        }
        bf16x8 ah = *(const bf16x8*)(&Wh[lane >> 4][wid * 16 + (lane & 15)][0]);
        bf16x8 al = *(const bf16x8*)(&Wo_[lane >> 4][wid * 16 + (lane & 15)][0]);
        #pragma unroll
        for (int nf = 0; nf < 4; ++nf) {
            bf16x8 bh = *(const bf16x8*)(&Xh[lane >> 4][nf * 16 + (lane & 15)][0]);
            bf16x8 bl = *(const bf16x8*)(&Xo[lane >> 4][nf * 16 + (lane & 15)][0]);
            acc[nf] = __builtin_amdgcn_mfma_f32_16x16x32_bf16(al, bh, acc[nf], 0, 0, 0);
            acc[nf] = __builtin_amdgcn_mfma_f32_16x16x32_bf16(ah, bl, acc[nf], 0, 0, 0);
            acc[nf] = __builtin_amdgcn_mfma_f32_16x16x32_bf16(ah, bh, acc[nf], 0, 0, 0);
        }
        __syncthreads();
    }
    int colp = lane & 15, rquad = lane >> 4;
    #pragma unroll
    for (int nf = 0; nf < 4; ++nf) {
        int p = pbase + nf * 16 + colp;
        int n = p / HWc; int rr = p - n * HWc;
        int hc = rr / Wc, wc = rr - hc * Wc;
        int ho = 2 * hc + hbit, wo = 2 * wc + wbit;
        #pragma unroll
        for (int r = 0; r < 4; ++r) {
            int m = m0 + wid * 16 + rquad * 4 + r;
            size_t idx = (((size_t)n * M + m) * Ho + ho) * Wo + wo;
            float v = acc[nf][r];
            if (emode == 0)      out[idx] = aux[idx] - v;
            else if (emode == 1) out[idx] = v;
            else                 atomicAdd(&out[idx], v);
        }
    }
}

// ---------------- fp32 implicit-GEMM forward conv (L0, L5) ----------------
template <int KK, int Kk, int S, int P>
__global__ __launch_bounds__(BLK) void conv_gemm(
    const float* __restrict__ Wp, const float* __restrict__ x,
    const float* __restrict__ yin, float* __restrict__ out,
    int M, int Ktot, int Cx, int Hx, int Wx, int Hout, int Wout,
    int kchunk, int emode)
{
    __shared__ float Wt[16][64];
    __shared__ float Xt[16][64];
    int tid = threadIdx.x, tx = tid & 15, ty = tid >> 4;
    int HW = Hout * Wout, HWx = Hx * Wx;
    int pbase = blockIdx.x * 64 + tx * 4;
    int n_[4], ho_[4], wo_[4];
    const float* xb_[4];
    #pragma unroll
    for (int j = 0; j < 4; ++j) {
        int p = pbase + j; int n = p / HW; int r = p - n * HW;
        int ho = r / Wout; int wo = r - ho * Wout;
        n_[j] = n; ho_[j] = ho; wo_[j] = wo;
        xb_[j] = x + (size_t)n * Cx * HWx;
    }
    int m0 = blockIdx.y * 64;
    int kb = blockIdx.z * kchunk, ke = kb + kchunk;
    if (ke > Ktot) ke = Ktot;
    float acc[4][4] = {};
    for (int k0 = kb; k0 < ke; k0 += 16) {
        int kr = k0 + ty;
        *(float4*)&Wt[ty][tx * 4] = *(const float4*)&Wp[(size_t)kr * M + m0 + tx * 4];
        int ci = kr / KK; int t = kr - ci * KK; int kh = t / Kk; int kw = t - kh * Kk;
        int cio = ci * HWx;
        float g[4];
        #pragma unroll
        for (int j = 0; j < 4; ++j) {
            int h = ho_[j] * S - P + kh, w = wo_[j] * S - P + kw;
            g[j] = ((unsigned)h < (unsigned)Hx && (unsigned)w < (unsigned)Wx)
                 ? xb_[j][cio + h * Wx + w] : 0.f;
        }
        *(float4*)&Xt[ty][tx * 4] = make_float4(g[0], g[1], g[2], g[3]);
        __syncthreads();
        #pragma unroll
        for (int kk = 0; kk < 16; ++kk) {
            float4 a = *(float4*)&Wt[kk][ty * 4];
            float4 b = *(float4*)&Xt[kk][tx * 4];
            float aa[4] = {a.x, a.y, a.z, a.w};
            float bb[4] = {b.x, b.y, b.z, b.w};
            #pragma unroll
            for (int i = 0; i < 4; ++i)
                #pragma unroll
                for (int j = 0; j < 4; ++j)
                    acc[i][j] = fmaf(aa[i], bb[j], acc[i][j]);
        }
        __syncthreads();
    }
    #pragma unroll
    for (int i = 0; i < 4; ++i) {
        int m = m0 + ty * 4 + i;
        #pragma unroll
        for (int j = 0; j < 4; ++j) {
            size_t idx = (((size_t)n_[j] * M + m) * Hout + ho_[j]) * Wout + wo_[j];
            float v = acc[i][j];
            if (emode == 0)      out[idx] = fmaxf(MU_F * v - THR_F, 0.f);
            else if (emode == 1) out[idx] = fmaxf(yin[idx] + MU_F * v - THR_F, 0.f);
            else                 atomicAdd(&out[idx], v);
        }
    }
}

// ---------------- 1x1-source transpose conv as plain GEMM (L5) ----------------
__global__ __launch_bounds__(BLK) void outer_gemm(
    const float* __restrict__ Wp, const float* __restrict__ zin,
    const float* __restrict__ aux, float* __restrict__ out,
    int M, int Kz, int emode)
{
    __shared__ float Wt[16][64];
    __shared__ float Xt[16][64];
    int tid = threadIdx.x, tx = tid & 15, ty = tid >> 4;
    int m0 = blockIdx.y * 64;
    float acc[4][4] = {};
    for (int k0 = 0; k0 < Kz; k0 += 16) {
        int kr = k0 + ty;
        *(float4*)&Wt[ty][tx * 4] = *(const float4*)&Wp[(size_t)kr * M + m0 + tx * 4];
        float g[4];
        #pragma unroll
        for (int j = 0; j < 4; ++j) g[j] = zin[(size_t)(tx * 4 + j) * Kz + kr];
        *(float4*)&Xt[ty][tx * 4] = make_float4(g[0], g[1], g[2], g[3]);
        __syncthreads();
        #pragma unroll
        for (int kk = 0; kk < 16; ++kk) {
            float4 a = *(float4*)&Wt[kk][ty * 4];
            float4 b = *(float4*)&Xt[kk][tx * 4];
            float aa[4] = {a.x, a.y, a.z, a.w};
            float bb[4] = {b.x, b.y, b.z, b.w};
            #pragma unroll
            for (int i = 0; i < 4; ++i)
                #pragma unroll
                for (int j = 0; j < 4; ++j)
                    acc[i][j] = fmaf(aa[i], bb[j], acc[i][j]);
        }
        __syncthreads();
    }
    #pragma unroll
    for (int i = 0; i < 4; ++i) {
        int m = m0 + ty * 4 + i;
        #pragma unroll
        for (int j = 0; j < 4; ++j) {
            int n = tx * 4 + j;
            size_t idx = (size_t)n * M + m;
            float v = acc[i][j];
            out[idx] = (emode == 0) ? (aux[idx] - v) : v;
        }
    }
}

// ---------------- M=3 transpose conv (image space, fp32) ----------------
__global__ __launch_bounds__(BLK) void convt_m3(
    const float* __restrict__ Wkc0, const float* __restrict__ z,
    const float* __restrict__ aux, float* __restrict__ out,
    int Cz, int Hz, int Wz, int Ho, int Wo, int emode)
{
    __shared__ float Wl[64 * 4 * 3];
    int tid = threadIdx.x;
    int hbit = blockIdx.z >> 1, wbit = blockIdx.z & 1;
    int khp = 1 - hbit, kwp = 1 - wbit;
    int Ktot = Cz * 4;
    for (int kidx = tid; kidx < Ktot; kidx += BLK) {
        int cz = kidx >> 2, t = kidx & 3, ti = t >> 1, tj = t & 1;
        int tap = (khp + 2 * ti) * 4 + (kwp + 2 * tj);
        Wl[kidx * 3 + 0] = Wkc0[(0 * 16 + tap) * 64 + cz];
        Wl[kidx * 3 + 1] = Wkc0[(1 * 16 + tap) * 64 + cz];
        Wl[kidx * 3 + 2] = Wkc0[(2 * 16 + tap) * 64 + cz];
    }
    __syncthreads();
    int Hc = Ho >> 1, Wc = Wo >> 1, HWc = Hc * Wc;
    int p = blockIdx.x * BLK + tid;
    int n = p / HWc, r = p - n * HWc, hc = r / Wc, wc = r - (r / Wc) * Wc;
    const float* zb = z + (size_t)n * Cz * Hz * Wz;
    int offs[4]; bool val[4];
    #pragma unroll
    for (int t = 0; t < 4; ++t) {
        int ti = t >> 1, tj = t & 1;
        int hn = hc + hbit - ti, wn = wc + wbit - tj;
        val[t] = ((unsigned)hn < (unsigned)Hz) && ((unsigned)wn < (unsigned)Wz);
        offs[t] = hn * Wz + wn;
    }
    float a0 = 0.f, a1 = 0.f, a2 = 0.f;
    int HWz = Hz * Wz;
    for (int cz = 0; cz < Cz; ++cz) {
        const float* base = zb + cz * HWz;
        #pragma unroll
        for (int t = 0; t < 4; ++t) {
            float g = val[t] ? base[offs[t]] : 0.f;
            int wi = (cz * 4 + t) * 3;
            a0 = fmaf(g, Wl[wi + 0], a0);
            a1 = fmaf(g, Wl[wi + 1], a1);
            a2 = fmaf(g, Wl[wi + 2], a2);
        }
    }
    int ho = 2 * hc + hbit, wo = 2 * wc + wbit;
    #pragma unroll
    for (int u = 0; u < 3; ++u) {
        float v = (u == 0) ? a0 : (u == 1) ? a1 : a2;
        size_t idx = (((size_t)n * 3 + u) * Ho + ho) * Wo + wo;
        out[idx] = (emode == 0) ? (aux[idx] - v) : tanhf(v);
    }
}

// ---------------- vectorized epilogues / elementwise (n % 4 == 0) ----------------
__global__ __launch_bounds__(BLK) void shrink_epi_v4(
    const float* __restrict__ p, const float* __restrict__ y,
    float* __restrict__ o, int n4, int mode)
{
    int i = blockIdx.x * BLK + threadIdx.x;
    if (i >= n4) return;
    float4 pv = ((const float4*)p)[i];
    float4 r;
    if (mode == 1) {
        float4 yv = ((const float4*)y)[i];
        r.x = fmaxf(yv.x + MU_F * pv.x - THR_F, 0.f);
        r.y = fmaxf(yv.y + MU_F * pv.y - THR_F, 0.f);
        r.z = fmaxf(yv.z + MU_F * pv.z - THR_F, 0.f);
        r.w = fmaxf(yv.w + MU_F * pv.w - THR_F, 0.f);
    } else {
        r.x = fmaxf(MU_F * pv.x - THR_F, 0.f);
        r.y = fmaxf(MU_F * pv.y - THR_F, 0.f);
        r.z = fmaxf(MU_F * pv.z - THR_F, 0.f);
        r.w = fmaxf(MU_F * pv.w - THR_F, 0.f);
    }
    ((float4*)o)[i] = r;
}

__global__ __launch_bounds__(BLK) void res_epi_v4(
    const float* __restrict__ aux, const float* __restrict__ acc,
    float* __restrict__ o, int n4)
{
    int i = blockIdx.x * BLK + threadIdx.x;
    if (i >= n4) return;
    float4 a = ((const float4*)aux)[i];
    float4 b = ((const float4*)acc)[i];
    ((float4*)o)[i] = make_float4(a.x - b.x, a.y - b.y, a.z - b.z, a.w - b.w);
}

__global__ __launch_bounds__(BLK) void y_update_v4(
    const float* __restrict__ z, const float* __restrict__ zo,
    float* __restrict__ y, int n4, float c)
{
    int i = blockIdx.x * BLK + threadIdx.x;
    if (i >= n4) return;
    float4 zv = ((const float4*)z)[i];
    float4 ov = ((const float4*)zo)[i];
    ((float4*)y)[i] = make_float4(
        fmaf(c, zv.x - ov.x, zv.x), fmaf(c, zv.y - ov.y, zv.y),
        fmaf(c, zv.z - ov.z, zv.z), fmaf(c, zv.w - ov.w, zv.w));
}

// ---------------- two-stage BN stats ----------------
__global__ __launch_bounds__(BLK) void bn_stats_part(
    const float* __restrict__ x, float* __restrict__ stats,
    int N, int C, int HW, int nblk)
{
    int c = blockIdx.x, b = blockIdx.y;
    int cnt = N * HW;
    float s = 0.f, s2 = 0.f;
    for (int i = b * BLK + threadIdx.x; i < cnt; i += nblk * BLK) {
        int n = i / HW, hw = i - n * HW;
        float v = x[((size_t)n * C + c) * HW + hw];
        s += v; s2 = fmaf(v, v, s2);
    }
    float ts  = blk_reduce(s);
    float ts2 = blk_reduce(s2);
    if (threadIdx.x == 0) {
        atomicAdd(&stats[c], ts);
        atomicAdd(&stats[C + c], ts2);
    }
}
__global__ __launch_bounds__(BLK) void bn_finalize(
    const float* __restrict__ stats, float* __restrict__ mean,
    float* __restrict__ rstd, int C, int cnt)
{
    int c = blockIdx.x * BLK + threadIdx.x;
    if (c >= C) return;
    float m = stats[c] / cnt;
    float var = stats[C + c] / cnt - m * m;
    mean[c] = m;
    rstd[c] = rsqrtf(var + 1e-5f);
}

// ---------------- BN apply + activation, vectorized ----------------
__global__ __launch_bounds__(BLK) void bn_act_v4(
    const float* __restrict__ x, const float* __restrict__ mean,
    const float* __restrict__ rstd, float* __restrict__ out,
    int n4, int C, int HW, int use_bn, int act)
{
    int i = blockIdx.x * BLK + threadIdx.x;
    if (i >= n4) return;
    float4 v = ((const float4*)x)[i];
    float e[4] = {v.x, v.y, v.z, v.w};
    int base = i * 4;
    #pragma unroll
    for (int j = 0; j < 4; ++j) {
        float t = e[j];
        if (use_bn) { int c = ((base + j) / HW) % C; t = (t - mean[c]) * rstd[c]; }
        e[j] = (act == 0) ? ((t >= 0.f) ? t : 0.2f * t) : fmaxf(t, 0.f);
    }
    ((float4*)out)[i] = make_float4(e[0], e[1], e[2], e[3]);
}

// ---------------- per-row L2 normalize ----------------
__global__ __launch_bounds__(128) void rownorm_kernel(
    const float* __restrict__ z, float* __restrict__ out, float* __restrict__ zvec)
{
    __shared__ float sh[128];
    int r = blockIdx.x, tid = threadIdx.x;
    float v = z[r * 128 + tid];
    sh[tid] = v * v;
    __syncthreads();
    #pragma unroll
    for (int s = 64; s > 0; s >>= 1) {
        if (tid < s) sh[tid] += sh[tid + s];
        __syncthreads();
    }
    float nrm = fmaxf(sqrtf(sh[0]), 1e-12f);
    float o = v / nrm;
    out[r * 128 + tid] = o;
    zvec[r * 128 + tid] = o;
}

static inline int gdiv(int a, int b) { return (a + b - 1) / b; }

extern "C" void kernel_launch(void* const* d_in, const int* in_sizes, int n_in,
                              void* d_out, int out_size, void* d_ws, size_t ws_size,
                              hipStream_t stream)
{
    const float* x = (const float*)d_in[0];
    const float* W[6];
    for (int i = 0; i < 6; ++i) W[i] = (const float*)d_in[1 + i];
    float* ws  = (float*)d_ws;
    float* out = (float*)d_out;

    const int Cin[6]  = {3, 64, 128, 256, 512, 1024};
    const int Cout[6] = {64, 128, 256, 512, 1024, 128};
    const int Hin[6]  = {96, 48, 24, 12, 6, 3};
    const int Hout[6] = {48, 24, 12, 6, 3, 1};
    const int N = 64;
    const int SKc[6] = {1, 1, 2, 4, 8, 1};
    const int SKt[6] = {1, 1, 1, 2, 4, 1};

    // ---- workspace layout: ~66.53M floats = 253.8 MB ----
    size_t off = 0;
    float* Wkc0 = ws + off; off += 3072;
    float* Wkc5 = ws + off; off += 1179648;
    float* Wn5  = ws + off; off += 1179648;
    const size_t csz[5] = {0, 131072, 524288, 2097152, 8388608};
    short* Cpk[5]; short* Tpk[5];
    {
        short* sbase = (short*)(ws + off);
        size_t soff = 0;
        for (int L = 1; L < 5; ++L) { Cpk[L] = sbase + soff; soff += 2 * csz[L]; }
        for (int L = 1; L < 5; ++L) { Tpk[L] = sbase + soff; soff += 2 * csz[L]; }
        off += soff / 2;
    }
    const size_t POOL = 30081024;
    float* pool = ws + off; off += POOL;
    float* xb   = ws + off; off += 9437184;
    float* mean = ws + off; off += 1024;
    float* rstd = ws + off; off += 1024;
    float* stats= ws + off; off += 2048;
    float* zvec = ws + off; off += 8192;
    float* pbuf = ws + off; off += 2359296;

    // ---- normalize + pack dictionaries ----
    wnorm_pack<<<64, BLK, 0, stream>>>(W[0], Wkc0, nullptr, 64, 48);
    for (int L = 1; L < 5; ++L)
        wnorm_pack_bf16<<<Cout[L], BLK, 0, stream>>>(W[L], Cpk[L], Tpk[L], Cout[L], Cin[L]);
    wnorm_pack<<<128, BLK, 0, stream>>>(W[5], Wkc5, Wn5, 128, 9216);

    // ---- FISTA momentum coefficients ----
    double td = 1.0; float cc[3];
    for (int i = 0; i < 3; ++i) {
        double tn = (1.0 + sqrt(1.0 + 4.0 * td * td)) * 0.5;
        cc[i] = (float)((td - 1.0) / tn);
        td = tn;
    }

    auto run_bn_stats = [&](const float* src, int C, int HW) {
        int cnt = N * HW;
        int nblk = 2048 / C; if (nblk < 1) nblk = 1;
        int maxb = gdiv(cnt, BLK); if (nblk > maxb) nblk = maxb;
        hipMemsetAsync(stats, 0, 2 * C * sizeof(float), stream);
        bn_stats_part<<<dim3(C, nblk), BLK, 0, stream>>>(src, stats, N, C, HW, nblk);
        bn_finalize<<<gdiv(C, BLK), BLK, 0, stream>>>(stats, mean, rstd, C, cnt);
    };

    const float* in = x;
    for (int L = 0; L < 6; ++L) {
        int zTot = N * Cout[L] * Hout[L] * Hout[L];
        int xTot = N * Cin[L] * Hin[L] * Hin[L];
        int npix = N * Hout[L] * Hout[L];
        dim3 ge4(gdiv(zTot / 4, BLK));
        dim3 gr4(gdiv(xTot / 4, BLK));

        float* zA = pool;
        float* zB = pool + (size_t)zTot;
        float* yb = pool + (size_t)2 * zTot;
        float* rb = pool + (size_t)3 * zTot;

        auto launch_conv = [&](const float* src, const float* y, float* dst, int mode) {
            if (L == 5) {
                hipMemsetAsync(pbuf, 0, (size_t)zTot * 4, stream);
                conv_gemm<9, 3, 1, 0><<<dim3(1, 2, 72), BLK, 0, stream>>>(Wkc5, src,
                    nullptr, pbuf, 128, 9216, 1024, 3, 3, 1, 1, 128, 2);
                shrink_epi_v4<<<gdiv(zTot / 4, BLK), BLK, 0, stream>>>(pbuf, y, dst, zTot / 4, mode);
            } else if (L == 0) {
                conv_gemm<16, 4, 2, 1><<<dim3(npix / 64, 1), BLK, 0, stream>>>(
                    Wkc0, src, y, dst, 64, 48, 3, 96, 96, 48, 48, 48, mode);
            } else if (SKc[L] == 1) {
                conv_gemm_bf16<<<dim3(npix / 64, Cout[L] / 64), BLK, 0, stream>>>(
                    Cpk[L], src, y, dst, Cout[L], Cin[L], Hin[L], Hin[L],
                    Hout[L], Hout[L], Cin[L] * 16, mode);
            } else {
                int sk = SKc[L];
                hipMemsetAsync(pbuf, 0, (size_t)zTot * 4, stream);
                conv_gemm_bf16<<<dim3(npix / 64, Cout[L] / 64, sk), BLK, 0, stream>>>(
                    Cpk[L], src, nullptr, pbuf, Cout[L], Cin[L], Hin[L], Hin[L],
                    Hout[L], Hout[L], Cin[L] * 16 / sk, 2);
                shrink_epi_v4<<<gdiv(zTot / 4, BLK), BLK, 0, stream>>>(pbuf, y, dst, zTot / 4, mode);
            }
        };

        // z0 = shrink(MU * conv(in))
        launch_conv(in, nullptr, zA, 0);

        float* z = zA; float* zo = zB;
        for (int it = 0; it < 3; ++it) {
            const float* ybp;
            if (it == 0) {
                ybp = z;                 // c = 0 -> y == z
            } else {
                y_update_v4<<<ge4, BLK, 0, stream>>>(z, zo, yb, zTot / 4, cc[it]);
                ybp = yb;
            }
            // r = in - convT(y)
            if (L == 0) {
                convt_m3<<<dim3(N * 48 * 48 / BLK, 1, 4), BLK, 0, stream>>>(
                    Wkc0, ybp, in, rb, 64, 48, 48, 96, 96, 0);
            } else if (L < 5) {
                int xpixc = N * (Hin[L] / 2) * (Hin[L] / 2);
                int sk = SKt[L];
                if (sk == 1) {
                    convt_gemm_bf16<<<dim3(xpixc / 64, Cin[L] / 64, 4), BLK, 0, stream>>>(
                        Tpk[L], ybp, in, rb, Cin[L], Cout[L], Hout[L], Hout[L],
                        Hin[L], Hin[L], 0, 1);
                } else {
                    hipMemsetAsync(rb, 0, (size_t)xTot * 4, stream);
                    convt_gemm_bf16<<<dim3(xpixc / 64, Cin[L] / 64, 4 * sk), BLK, 0, stream>>>(
                        Tpk[L], ybp, nullptr, rb, Cin[L], Cout[L], Hout[L], Hout[L],
                        Hin[L], Hin[L], 2, sk);
                    res_epi_v4<<<gr4, BLK, 0, stream>>>(in, rb, rb, xTot / 4);
                }
            } else {
                outer_gemm<<<dim3(1, 144), BLK, 0, stream>>>(Wn5, ybp, in, rb, 9216, 128, 0);
            }
            // z_new = shrink(y + MU*conv(r))
            launch_conv(rb, ybp, zo, 1);
            float* tmp = z; z = zo; zo = tmp;
        }

        int HW = Hout[L] * Hout[L];
        if (L == 0) {
            bn_act_v4<<<ge4, BLK, 0, stream>>>(z, nullptr, nullptr, xb, zTot / 4, Cout[L], HW, 0, 0);
            in = xb;
        } else if (L < 5) {
            run_bn_stats(z, Cout[L], HW);
            bn_act_v4<<<ge4, BLK, 0, stream>>>(z, mean, rstd, xb, zTot / 4, Cout[L], HW, 1, 0);
            in = xb;
        } else {
            rownorm_kernel<<<64, 128, 0, stream>>>(z, out, zvec);
        }
    }

    // ---- decoder (bf16x3 convT stages, fp32 elsewhere) ----
    float* zA = pool;
    float* zB = pool + 9437184;
    {
        int oT = N * 1024 * 9;
        outer_gemm<<<dim3(1, 144), BLK, 0, stream>>>(Wn5, zvec, nullptr, zA, 9216, 128, 1);
        run_bn_stats(zA, 1024, 9);
        bn_act_v4<<<gdiv(oT / 4, BLK), BLK, 0, stream>>>(zA, mean, rstd, zB, oT / 4, 1024, 9, 1, 1);
    }
    float* cur = zB;
    for (int i = 4; i >= 1; --i) {
        int oT = N * Cin[i] * Hin[i] * Hin[i];
        int xpixc = N * (Hin[i] / 2) * (Hin[i] / 2);
        int sk = SKt[i];
        if (sk == 1) {
            convt_gemm_bf16<<<dim3(xpixc / 64, Cin[i] / 64, 4), BLK, 0, stream>>>(
                Tpk[i], cur, nullptr, zA, Cin[i], Cout[i], Hout[i], Hout[i],
                Hin[i], Hin[i], 1, 1);
        } else {
            hipMemsetAsync(zA, 0, (size_t)oT * 4, stream);
            convt_gemm_bf16<<<dim3(xpixc / 64, Cin[i] / 64, 4 * sk), BLK, 0, stream>>>(
                Tpk[i], cur, nullptr, zA, Cin[i], Cout[i], Hout[i], Hout[i],
                Hin[i], Hin[i], 2, sk);
        }
        run_bn_stats(zA, Cin[i], Hin[i] * Hin[i]);
        bn_act_v4<<<gdiv(oT / 4, BLK), BLK, 0, stream>>>(zA, mean, rstd, zB, oT / 4,
            Cin[i], Hin[i] * Hin[i], 1, 1);
        cur = zB;
    }
    convt_m3<<<dim3(N * 48 * 48 / BLK, 1, 4), BLK, 0, stream>>>(
        Wkc0, cur, nullptr, out + 8192, 64, 48, 48, 96, 96, 2);
}